// Round 8
// baseline (844.811 us; speedup 1.0000x reference)
//
#include <hip/hip_runtime.h>
#include <math.h>

#define NN 100000
#define NE 1600000
#define NG 1024
#define FF 128
#define BSH 9
#define NBK ((NN + 511) >> BSH)   // 196 buckets of 512 nodes
#define RB 256                    // radix blocks

typedef __attribute__((ext_vector_type(8))) short short8;
typedef __attribute__((ext_vector_type(4))) float f32x4;

__device__ __forceinline__ unsigned short f2b(float f) {
    union { float f; unsigned u; } v; v.f = f;
    unsigned r = (v.u + 0x7FFF + ((v.u >> 16) & 1)) >> 16;
    return (unsigned short)r;
}
__device__ __forceinline__ float us2f(unsigned short u) {
    union { unsigned u; float f; } v; v.u = ((unsigned)u) << 16; return v.f;
}
__device__ __forceinline__ float b2f_lo(unsigned u) {
    union { unsigned u; float f; } v; v.u = u << 16; return v.f;
}
__device__ __forceinline__ float b2f_hi(unsigned u) {
    union { unsigned u; float f; } v; v.u = u & 0xFFFF0000u; return v.f;
}

// ---------------- radix pass 1: LDS-aggregated bucket histogram -------------
__global__ __launch_bounds__(256)
void radix_hist(const int* __restrict__ dst, int* __restrict__ bcnt, int n) {
    __shared__ int cnt[NBK];
    for (int i = threadIdx.x; i < NBK; i += 256) cnt[i] = 0;
    __syncthreads();
    const int per = (n + RB - 1) / RB;
    const int beg = blockIdx.x * per;
    const int end = min(n, beg + per);
    for (int i = beg + threadIdx.x; i < end; i += 256)
        atomicAdd(&cnt[dst[i] >> BSH], 1);
    __syncthreads();
    for (int i = threadIdx.x; i < NBK; i += 256)
        if (cnt[i]) atomicAdd(&bcnt[i], cnt[i]);
}

// ---------------- radix pass 2: scatter packed (src<<9|local) into buckets --
__global__ __launch_bounds__(256)
void radix_scatter(const int* __restrict__ src, const int* __restrict__ dst,
                   int* __restrict__ bcur, unsigned* __restrict__ pairs, int n) {
    __shared__ int base[NBK];
    __shared__ int cnt[NBK];
    for (int i = threadIdx.x; i < NBK; i += 256) cnt[i] = 0;
    __syncthreads();
    const int per = (n + RB - 1) / RB;
    const int beg = blockIdx.x * per;
    const int end = min(n, beg + per);
    for (int i = beg + threadIdx.x; i < end; i += 256)
        atomicAdd(&cnt[dst[i] >> BSH], 1);
    __syncthreads();
    for (int i = threadIdx.x; i < NBK; i += 256)
        base[i] = cnt[i] ? atomicAdd(&bcur[i], cnt[i]) : 0;
    __syncthreads();
    for (int i = beg + threadIdx.x; i < end; i += 256) {
        int d = dst[i];
        int p = atomicAdd(&base[d >> BSH], 1);
        pairs[p] = ((unsigned)src[i] << BSH) | (unsigned)(d & 511);
    }
}

// ---------------- radix pass 3: per-bucket hist+scan+scatter -> CSR ---------
__global__ __launch_bounds__(256)
void bucket_build(const unsigned* __restrict__ pairs, const int* __restrict__ boff,
                  int* __restrict__ row_off, float* __restrict__ inv_deg,
                  int* __restrict__ ssrc) {
    __shared__ int cnt[512];
    __shared__ int curs[512];
    __shared__ int wsum[4];
    const int b = blockIdx.x;
    const int n0 = b << BSH;
    const int t = threadIdx.x;
    const int lane = t & 63, wid = t >> 6;

    for (int i = t; i < 512; i += 256) cnt[i] = 0;
    __syncthreads();
    const int beg = boff[b], end = boff[b + 1];
    for (int i = beg + t; i < end; i += 256)
        atomicAdd(&cnt[pairs[i] & 511], 1);
    __syncthreads();

    int c0 = cnt[2 * t], c1 = cnt[2 * t + 1];
    int v = c0 + c1;
    int x = v;
    #pragma unroll
    for (int o = 1; o < 64; o <<= 1) {
        int y = __shfl_up(x, o);
        if (lane >= o) x += y;
    }
    if (lane == 63) wsum[wid] = x;
    __syncthreads();
    if (t == 0) {
        int s = 0;
        #pragma unroll
        for (int w2 = 0; w2 < 4; ++w2) { int tv = wsum[w2]; wsum[w2] = s; s += tv; }
    }
    __syncthreads();
    int g0 = beg + wsum[wid] + x - v;
    int g1 = g0 + c0;
    curs[2 * t] = g0;
    curs[2 * t + 1] = g1;
    {
        int node = n0 + 2 * t;
        if (node < NN) { row_off[node] = g0; inv_deg[node] = 1.0f / (float)(c0 > 1 ? c0 : 1); }
        node = n0 + 2 * t + 1;
        if (node < NN) { row_off[node] = g1; inv_deg[node] = 1.0f / (float)(c1 > 1 ? c1 : 1); }
    }
    __syncthreads();
    for (int i = beg + t; i < end; i += 256) {
        unsigned pr = pairs[i];
        int p = atomicAdd(&curs[pr & 511], 1);
        ssrc[p] = (int)(pr >> BSH);
    }
    if (b == 0 && t == 0) row_off[NN] = boff[NBK];
}

// ---------------- graph offsets via binary search on sorted batch -----------
__global__ __launch_bounds__(256)
void graph_offsets(const int* __restrict__ batch, int* __restrict__ g_off,
                   float* __restrict__ inv_cnt) {
    int g = blockIdx.x * blockDim.x + threadIdx.x;
    if (g > NG) return;
    if (g == NG) { g_off[NG] = NN; return; }
    int lo = 0, hi = NN;
    while (lo < hi) { int mid = (lo + hi) >> 1; if (batch[mid] < g) lo = mid + 1; else hi = mid; }
    int lo2 = lo, hi2 = NN;
    while (lo2 < hi2) { int mid = (lo2 + hi2) >> 1; if (batch[mid] < g + 1) lo2 = mid + 1; else hi2 = mid; }
    g_off[g] = lo;
    int c = lo2 - lo;
    inv_cnt[g] = 1.0f / (float)(c > 1 ? c : 1);
}

// ---------------- exclusive scan (only for 196 bucket counts) ---------------
__global__ __launch_bounds__(1024)
void scan_hist(const int* __restrict__ in, int* __restrict__ off_out,
               int* __restrict__ cur_out, int n) {
    __shared__ int wsum[16];
    __shared__ int carry_s;
    const int t = threadIdx.x, lane = t & 63, wid = t >> 6;
    if (t == 0) carry_s = 0;
    __syncthreads();
    for (int base = 0; base < n; base += 1024) {
        int i = base + t;
        int v = (i < n) ? in[i] : 0;
        int x = v;
        #pragma unroll
        for (int o = 1; o < 64; o <<= 1) {
            int y = __shfl_up(x, o);
            if (lane >= o) x += y;
        }
        if (lane == 63) wsum[wid] = x;
        __syncthreads();
        if (t == 0) {
            int s = carry_s;
            #pragma unroll
            for (int w2 = 0; w2 < 16; ++w2) { int tv = wsum[w2]; wsum[w2] = s; s += tv; }
            carry_s = s;
        }
        __syncthreads();
        int excl = wsum[wid] + x - v;
        if (i < n) {
            off_out[i] = excl;
            if (cur_out) cur_out[i] = excl;
        }
        __syncthreads();
    }
    if (t == 0) off_out[n] = carry_s;
}

// ---------------- weight prep: fp32 [k][n] -> bf16 [n][k] ----------------
struct WTab { const float* a[16]; };
__global__ __launch_bounds__(256)
void prep_weights(WTab tab, unsigned short* __restrict__ dst) {
    int w = blockIdx.x >> 6;
    int idx = ((blockIdx.x & 63) << 8) + threadIdx.x;
    int k = idx >> 7, n = idx & 127;
    dst[(size_t)w * 16384 + n * 128 + k] = f2b(tab.a[w][idx]);
}

// ---------------- SAGE mean aggregation ----------------
__global__ __launch_bounds__(256)
void sage_agg(const unsigned short* __restrict__ hb, const int* __restrict__ row_off,
              const int* __restrict__ ssrc, const float* __restrict__ inv_deg,
              unsigned short* __restrict__ aggb) {
    const int wid = threadIdx.x >> 6;
    const int lane = threadIdx.x & 63;
    const int node = blockIdx.x * 4 + wid;
    const int eg = lane >> 4, j = lane & 15;
    const int beg = row_off[node], end = row_off[node + 1];
    float a[8] = {0.f, 0.f, 0.f, 0.f, 0.f, 0.f, 0.f, 0.f};
    int e = beg + eg;
    for (; e + 4 < end; e += 8) {
        int s0 = ssrc[e], s1 = ssrc[e + 4];
        uint4 v0 = *(const uint4*)&hb[(size_t)s0 * FF + j * 8];
        uint4 v1 = *(const uint4*)&hb[(size_t)s1 * FF + j * 8];
        a[0] += b2f_lo(v0.x) + b2f_lo(v1.x); a[1] += b2f_hi(v0.x) + b2f_hi(v1.x);
        a[2] += b2f_lo(v0.y) + b2f_lo(v1.y); a[3] += b2f_hi(v0.y) + b2f_hi(v1.y);
        a[4] += b2f_lo(v0.z) + b2f_lo(v1.z); a[5] += b2f_hi(v0.z) + b2f_hi(v1.z);
        a[6] += b2f_lo(v0.w) + b2f_lo(v1.w); a[7] += b2f_hi(v0.w) + b2f_hi(v1.w);
    }
    if (e < end) {
        int s0 = ssrc[e];
        uint4 v0 = *(const uint4*)&hb[(size_t)s0 * FF + j * 8];
        a[0] += b2f_lo(v0.x); a[1] += b2f_hi(v0.x);
        a[2] += b2f_lo(v0.y); a[3] += b2f_hi(v0.y);
        a[4] += b2f_lo(v0.z); a[5] += b2f_hi(v0.z);
        a[6] += b2f_lo(v0.w); a[7] += b2f_hi(v0.w);
    }
    #pragma unroll
    for (int k = 0; k < 8; ++k) {
        a[k] += __shfl_xor(a[k], 16);
        a[k] += __shfl_xor(a[k], 32);
    }
    if (eg == 0) {
        float id = inv_deg[node];
        uint4 o;
        o.x = (unsigned)f2b(a[0] * id) | ((unsigned)f2b(a[1] * id) << 16);
        o.y = (unsigned)f2b(a[2] * id) | ((unsigned)f2b(a[3] * id) << 16);
        o.z = (unsigned)f2b(a[4] * id) | ((unsigned)f2b(a[5] * id) << 16);
        o.w = (unsigned)f2b(a[6] * id) | ((unsigned)f2b(a[7] * id) << 16);
        *(uint4*)&aggb[(size_t)node * FF + j * 8] = o;
    }
}

// ---------------- mean pool per graph from bf16 ----------------
__global__ __launch_bounds__(128)
void pool_mean_b(const unsigned short* __restrict__ src, const int* __restrict__ g_off,
                 const float* __restrict__ inv_cnt, float* __restrict__ out) {
    const int g = blockIdx.x;
    const int j = threadIdx.x;
    const int beg = g_off[g], end = g_off[g + 1];
    float s = 0.f;
    for (int n = beg; n < end; ++n) s += us2f(src[(size_t)n * FF + j]);
    out[(size_t)g * FF + j] = s * inv_cnt[g];
}

// ---------------- MFMA bf16 GEMM, W from global (L2-resident) ---------------
template<bool AB16, bool R1, int RESM, int ACT, bool LN, bool OF32, bool OB16>
__global__ __launch_bounds__(256)
void gemm_mfma(const void* __restrict__ A_,
               const unsigned short* __restrict__ Wt,
               const float* __restrict__ bias,
               const float* __restrict__ rvec, const float* __restrict__ rrow,
               const float* __restrict__ res,
               const float* __restrict__ lng, const float* __restrict__ lnb,
               float* __restrict__ outf, unsigned short* __restrict__ outb, int M) {
    __shared__ short Al[64 * 136];

    const int t = threadIdx.x;
    const int lane = t & 63, wid = t >> 6;
    const int m0 = blockIdx.x * 64;
    const int cb = lane & 15, rq = lane >> 4;

    if (AB16) {
        const unsigned short* Ab = (const unsigned short*)A_;
        for (int i = t; i < 1024; i += 256) {
            int row = i >> 4, seg = i & 15;
            int gr = m0 + row; if (gr >= M) gr = M - 1;
            *(uint4*)&Al[row * 136 + seg * 8] = *(const uint4*)&Ab[(size_t)gr * 128 + seg * 8];
        }
    } else {
        const float* Af = (const float*)A_;
        for (int i = t; i < 2048; i += 256) {
            int row = i >> 5, seg = i & 31;
            int gr = m0 + row; if (gr >= M) gr = M - 1;
            float4 v = *(const float4*)&Af[(size_t)gr * 128 + seg * 4];
            ushort4 o = {f2b(v.x), f2b(v.y), f2b(v.z), f2b(v.w)};
            *(ushort4*)&Al[row * 136 + seg * 4] = o;
        }
    }
    __syncthreads();

    f32x4 acc[8];
    #pragma unroll
    for (int nt = 0; nt < 8; ++nt) acc[nt] = (f32x4){0.f, 0.f, 0.f, 0.f};

    const int aoff_base = (wid * 16 + cb) * 136 + rq * 8;
    for (int kc = 0; kc < 4; ++kc) {
        short8 a0 = *(const short8*)&Al[aoff_base + kc * 32];
        #pragma unroll
        for (int nt = 0; nt < 8; ++nt) {
            short8 b0 = *(const short8*)&Wt[(size_t)(nt * 16 + cb) * 128 + kc * 32 + rq * 8];
            acc[nt] = __builtin_amdgcn_mfma_f32_16x16x32_bf16(a0, b0, acc[nt], 0, 0, 0);
        }
    }

    float bs[8], rr[8], lg[8], lb[8];
    #pragma unroll
    for (int nt = 0; nt < 8; ++nt) {
        int col = nt * 16 + cb;
        bs[nt] = bias[col];
        if (R1) rr[nt] = rrow[col];
        if (LN) { lg[nt] = lng[col]; lb[nt] = lnb[col]; }
    }
    #pragma unroll
    for (int reg = 0; reg < 4; ++reg) {
        int m = m0 + wid * 16 + rq * 4 + reg;
        int mc = m < M ? m : M - 1;
        float v[8];
        #pragma unroll
        for (int nt = 0; nt < 8; ++nt) v[nt] = acc[nt][reg] + bs[nt];
        if (R1) {
            float rv = rvec[mc];
            #pragma unroll
            for (int nt = 0; nt < 8; ++nt) v[nt] += rv * rr[nt];
        }
        if (RESM == 1) {
            #pragma unroll
            for (int nt = 0; nt < 8; ++nt) v[nt] += res[(size_t)mc * 128 + nt * 16 + cb];
        }
        if (ACT == 1) {
            #pragma unroll
            for (int nt = 0; nt < 8; ++nt) v[nt] = v[nt] > 0.f ? v[nt] : expm1f(v[nt]);
        }
        if (LN) {
            float s1 = 0.f, s2 = 0.f;
            #pragma unroll
            for (int nt = 0; nt < 8; ++nt) { s1 += v[nt]; s2 += v[nt] * v[nt]; }
            #pragma unroll
            for (int o = 8; o >= 1; o >>= 1) { s1 += __shfl_xor(s1, o); s2 += __shfl_xor(s2, o); }
            float mu = s1 * (1.f / 128.f);
            float rs = rsqrtf(s2 * (1.f / 128.f) - mu * mu + 1e-5f);
            #pragma unroll
            for (int nt = 0; nt < 8; ++nt) v[nt] = (v[nt] - mu) * rs * lg[nt] + lb[nt];
        }
        if (m < M) {
            #pragma unroll
            for (int nt = 0; nt < 8; ++nt) {
                size_t o = (size_t)m * 128 + nt * 16 + cb;
                if (OF32) outf[o] = v[nt];
                if (OB16) outb[o] = f2b(v[nt]);
            }
        }
    }
}

// ---------------- fused GEMM chain, W from global (3 barriers total) --------
// All A-reads and epilogue writes are band-local (wave's own 16 rows), so
// barriers are needed only when a whole LDS tile changes role.
__global__ __launch_bounds__(256)
void gc_chain(const unsigned short* __restrict__ hin, const unsigned short* __restrict__ aggb,
              unsigned short* __restrict__ hout,
              const unsigned short* __restrict__ Wl_t, const unsigned short* __restrict__ Wr_t,
              const unsigned short* __restrict__ W1_t, const unsigned short* __restrict__ W2_t,
              const float* __restrict__ bl,
              const float* __restrict__ g1, const float* __restrict__ b1,
              const float* __restrict__ bb1, const float* __restrict__ bb2,
              const float* __restrict__ g2, const float* __restrict__ b2, int M) {
    __shared__ short Hl[64 * 136];     // h tile -> y1 tile
    __shared__ short Gl[64 * 136];     // agg tile -> elu(t) tile

    const int t = threadIdx.x;
    const int lane = t & 63, wid = t >> 6;
    const int m0 = blockIdx.x * 64;
    const int cb = lane & 15, rq = lane >> 4;

    for (int i = t; i < 1024; i += 256) {
        int row = i >> 4, seg = i & 15;
        int gr = m0 + row; if (gr >= M) gr = M - 1;
        *(uint4*)&Hl[row * 136 + seg * 8] = *(const uint4*)&hin[(size_t)gr * 128 + seg * 8];
        *(uint4*)&Gl[row * 136 + seg * 8] = *(const uint4*)&aggb[(size_t)gr * 128 + seg * 8];
    }
    __syncthreads();

    f32x4 acc[8];
    const int aoff_base = (wid * 16 + cb) * 136 + rq * 8;

    // ---- dual GEMM: acc = agg@Wl + h@Wr (B-fragments straight from L2) ----
    #pragma unroll
    for (int nt = 0; nt < 8; ++nt) acc[nt] = (f32x4){0.f, 0.f, 0.f, 0.f};
    for (int kc = 0; kc < 4; ++kc) {
        short8 a0 = *(const short8*)&Gl[aoff_base + kc * 32];
        short8 a1 = *(const short8*)&Hl[aoff_base + kc * 32];
        #pragma unroll
        for (int nt = 0; nt < 8; ++nt) {
            const size_t wo = (size_t)(nt * 16 + cb) * 128 + kc * 32 + rq * 8;
            acc[nt] = __builtin_amdgcn_mfma_f32_16x16x32_bf16(a0, *(const short8*)&Wl_t[wo], acc[nt], 0, 0, 0);
            acc[nt] = __builtin_amdgcn_mfma_f32_16x16x32_bf16(a1, *(const short8*)&Wr_t[wo], acc[nt], 0, 0, 0);
        }
    }

    // ---- epilogue 1: y1 = LN1(acc + bl + h) -> Hl (band-local) ----
    float y1r[4][8];
    {
        float bs[8], lg[8], lb[8];
        #pragma unroll
        for (int nt = 0; nt < 8; ++nt) {
            int col = nt * 16 + cb;
            bs[nt] = bl[col]; lg[nt] = g1[col]; lb[nt] = b1[col];
        }
        #pragma unroll
        for (int reg = 0; reg < 4; ++reg) {
            int r = wid * 16 + rq * 4 + reg;
            float v[8];
            float s1 = 0.f, s2 = 0.f;
            #pragma unroll
            for (int nt = 0; nt < 8; ++nt) {
                v[nt] = acc[nt][reg] + bs[nt] + us2f((unsigned short)Hl[r * 136 + nt * 16 + cb]);
                s1 += v[nt]; s2 += v[nt] * v[nt];
            }
            #pragma unroll
            for (int o = 8; o >= 1; o >>= 1) { s1 += __shfl_xor(s1, o); s2 += __shfl_xor(s2, o); }
            float mu = s1 * (1.f / 128.f);
            float rs = rsqrtf(s2 * (1.f / 128.f) - mu * mu + 1e-5f);
            #pragma unroll
            for (int nt = 0; nt < 8; ++nt) {
                float y = (v[nt] - mu) * rs * lg[nt] + lb[nt];
                y1r[reg][nt] = y;
                Hl[r * 136 + nt * 16 + cb] = (short)f2b(y);
            }
        }
    }
    __syncthreads();   // Hl role change: h -> y1 (cross-lane A-reads next)

    // ---- FF1: t = elu(y1@W1 + bb1) -> Gl ----
    #pragma unroll
    for (int nt = 0; nt < 8; ++nt) acc[nt] = (f32x4){0.f, 0.f, 0.f, 0.f};
    for (int kc = 0; kc < 4; ++kc) {
        short8 a0 = *(const short8*)&Hl[aoff_base + kc * 32];
        #pragma unroll
        for (int nt = 0; nt < 8; ++nt) {
            const size_t wo = (size_t)(nt * 16 + cb) * 128 + kc * 32 + rq * 8;
            acc[nt] = __builtin_amdgcn_mfma_f32_16x16x32_bf16(a0, *(const short8*)&W1_t[wo], acc[nt], 0, 0, 0);
        }
    }
    {
        float bs[8];
        #pragma unroll
        for (int nt = 0; nt < 8; ++nt) bs[nt] = bb1[nt * 16 + cb];
        #pragma unroll
        for (int reg = 0; reg < 4; ++reg) {
            int r = wid * 16 + rq * 4 + reg;
            #pragma unroll
            for (int nt = 0; nt < 8; ++nt) {
                float v = acc[nt][reg] + bs[nt];
                v = v > 0.f ? v : expm1f(v);
                Gl[r * 136 + nt * 16 + cb] = (short)f2b(v);
            }
        }
    }
    __syncthreads();   // Gl role change: agg -> elu(t)

    // ---- FF2: h' = LN2(t@W2 + bb2 + y1) -> global (y1 from registers) ----
    #pragma unroll
    for (int nt = 0; nt < 8; ++nt) acc[nt] = (f32x4){0.f, 0.f, 0.f, 0.f};
    for (int kc = 0; kc < 4; ++kc) {
        short8 a0 = *(const short8*)&Gl[aoff_base + kc * 32];
        #pragma unroll
        for (int nt = 0; nt < 8; ++nt) {
            const size_t wo = (size_t)(nt * 16 + cb) * 128 + kc * 32 + rq * 8;
            acc[nt] = __builtin_amdgcn_mfma_f32_16x16x32_bf16(a0, *(const short8*)&W2_t[wo], acc[nt], 0, 0, 0);
        }
    }
    {
        float bs[8], lg[8], lb[8];
        #pragma unroll
        for (int nt = 0; nt < 8; ++nt) {
            int col = nt * 16 + cb;
            bs[nt] = bb2[col]; lg[nt] = g2[col]; lb[nt] = b2[col];
        }
        #pragma unroll
        for (int reg = 0; reg < 4; ++reg) {
            int r = wid * 16 + rq * 4 + reg;
            int m = m0 + r;
            float v[8];
            float s1 = 0.f, s2 = 0.f;
            #pragma unroll
            for (int nt = 0; nt < 8; ++nt) {
                v[nt] = acc[nt][reg] + bs[nt] + y1r[reg][nt];
                s1 += v[nt]; s2 += v[nt] * v[nt];
            }
            #pragma unroll
            for (int o = 8; o >= 1; o >>= 1) { s1 += __shfl_xor(s1, o); s2 += __shfl_xor(s2, o); }
            float mu = s1 * (1.f / 128.f);
            float rs = rsqrtf(s2 * (1.f / 128.f) - mu * mu + 1e-5f);
            if (m < M) {
                #pragma unroll
                for (int nt = 0; nt < 8; ++nt)
                    hout[(size_t)m * 128 + nt * 16 + cb] = f2b((v[nt] - mu) * rs * lg[nt] + lb[nt]);
            }
        }
    }
}

extern "C" void kernel_launch(void* const* d_in, const int* in_sizes, int n_in,
                              void* d_out, int out_size, void* d_ws, size_t ws_size,
                              hipStream_t stream) {
    const float* x      = (const float*)d_in[0];
    const float* w      = (const float*)d_in[1];
    const int*   ei     = (const int*)d_in[2];
    const int*   batch  = (const int*)d_in[3];
    const float* W_in   = (const float*)d_in[4];
    const float* b_in   = (const float*)d_in[5];
    const float* sage_Wl = (const float*)d_in[6];
    const float* sage_bl = (const float*)d_in[7];
    const float* sage_Wr = (const float*)d_in[8];
    const float* ln1_g  = (const float*)d_in[9];
    const float* ln1_b  = (const float*)d_in[10];
    const float* lin1_W = (const float*)d_in[11];
    const float* lin1_b = (const float*)d_in[12];
    const float* lin2_W = (const float*)d_in[13];
    const float* lin2_b = (const float*)d_in[14];
    const float* ln2_g  = (const float*)d_in[15];
    const float* ln2_b  = (const float*)d_in[16];
    const float* mdf_W  = (const float*)d_in[17];
    const float* mdf_b  = (const float*)d_in[18];
    const float* pln1_g = (const float*)d_in[19];
    const float* pln1_b = (const float*)d_in[20];
    const float* plin1_W = (const float*)d_in[21];
    const float* plin1_b = (const float*)d_in[22];
    const float* plin2_W = (const float*)d_in[23];
    const float* plin2_b = (const float*)d_in[24];
    const float* pln2_g = (const float*)d_in[25];
    const float* pln2_b = (const float*)d_in[26];
    float* out = (float*)d_out;

    const int* e_src = ei;
    const int* e_dst = ei + NE;

    // ---- workspace layout ----
    float* ws = (float*)d_ws;
    size_t off = 0;
    float* gm    = ws + off; off += (size_t)NG * FF;
    float* hh    = ws + off; off += (size_t)NG * FF;
    float* tt    = ws + off; off += (size_t)NG * FF;
    float* inv_deg = ws + off; off += NN;
    float* inv_cnt = ws + off; off += NG;
    unsigned short* us = (unsigned short*)(ws + off);
    size_t uoff = 0;
    unsigned short* hb0  = us + uoff; uoff += (size_t)NN * FF;
    unsigned short* hb1  = us + uoff; uoff += (size_t)NN * FF;
    unsigned short* aggb = us + uoff; uoff += (size_t)NN * FF;
    unsigned short* wt   = us + uoff; uoff += (size_t)16 * 16384;
    int* iw = (int*)(us + uoff);
    size_t ioff = 0;
    unsigned* pairs = (unsigned*)iw; ioff += NE;
    int* ssrc    = iw + ioff; ioff += NE;
    int* row_off = iw + ioff; ioff += NN + 1;
    int* g_off   = iw + ioff; ioff += NG + 1;
    int* bcnt    = iw + ioff; ioff += NBK;
    int* boff    = iw + ioff; ioff += NBK + 1;
    int* bcur    = iw + ioff; ioff += NBK;

    // ---- weight prep (16 matrices -> transposed bf16) ----
    WTab tab;
    tab.a[0] = W_in;
    for (int l = 0; l < 3; ++l) {
        tab.a[1 + l]  = sage_Wl + (size_t)l * 16384;
        tab.a[4 + l]  = sage_Wr + (size_t)l * 16384;
        tab.a[7 + l]  = lin1_W + (size_t)l * 16384;
        tab.a[10 + l] = lin2_W + (size_t)l * 16384;
    }
    tab.a[13] = mdf_W;      // first 128 rows only (Wa)
    tab.a[14] = plin1_W;
    tab.a[15] = plin2_W;
    prep_weights<<<16 * 64, 256, 0, stream>>>(tab, wt);
    const unsigned short* win_t = wt + 0 * 16384;
    const unsigned short* wa_t  = wt + 13 * 16384;
    const unsigned short* p1_t  = wt + 14 * 16384;
    const unsigned short* p2_t  = wt + 15 * 16384;

    // ---- build CSR (LDS-aggregated radix partition, no global scan) ----
    hipMemsetAsync(bcnt, 0, sizeof(int) * NBK, stream);
    radix_hist<<<RB, 256, 0, stream>>>(e_dst, bcnt, NE);
    scan_hist<<<1, 1024, 0, stream>>>(bcnt, boff, bcur, NBK);
    graph_offsets<<<(NG + 256) / 256, 256, 0, stream>>>(batch, g_off, inv_cnt);
    radix_scatter<<<RB, 256, 0, stream>>>(e_src, e_dst, bcur, pairs, NE);
    bucket_build<<<NBK, 256, 0, stream>>>(pairs, boff, row_off, inv_deg, ssrc);

    const int GN = (NN + 63) / 64;     // 1563
    const int GB = NG / 64;            // 16

    // ---- input linear: hb0 = bf16(x @ W_in[0:128] + w * W_in[128] + b_in) ----
    gemm_mfma<false, true, 0, 0, false, false, true><<<GN, 256, 0, stream>>>(
        x, win_t, b_in, w, W_in + 128 * 128,
        nullptr, nullptr, nullptr, nullptr, hb0, NN);

    // ---- 3 GC blocks: gather (high-occupancy) + fused GEMM chain ----
    unsigned short* hcur = hb0;
    unsigned short* hnxt = hb1;
    for (int l = 0; l < 3; ++l) {
        sage_agg<<<NN / 4, 256, 0, stream>>>(hcur, row_off, ssrc, inv_deg, aggb);
        gc_chain<<<GN, 256, 0, stream>>>(
            hcur, aggb, hnxt,
            wt + (size_t)(1 + l) * 16384, wt + (size_t)(4 + l) * 16384,
            wt + (size_t)(7 + l) * 16384, wt + (size_t)(10 + l) * 16384,
            sage_bl + (size_t)l * FF,
            ln1_g + (size_t)l * FF, ln1_b + (size_t)l * FF,
            lin1_b + (size_t)l * FF, lin2_b + (size_t)l * FF,
            ln2_g + (size_t)l * FF, ln2_b + (size_t)l * FF, NN);
        unsigned short* tmp = hcur; hcur = hnxt; hnxt = tmp;
    }

    // ---- head: pool(h2) == gm @ mdf_W[0:128] + mdf_b  (exact algebra) ----
    pool_mean_b<<<NG, 128, 0, stream>>>(hcur, g_off, inv_cnt, gm);
    gemm_mfma<false, false, 0, 0, true, true, false><<<GB, 256, 0, stream>>>(
        gm, wa_t, mdf_b, nullptr, nullptr,
        nullptr, pln1_g, pln1_b, hh, nullptr, NG);
    gemm_mfma<false, false, 0, 1, false, true, false><<<GB, 256, 0, stream>>>(
        hh, p1_t, plin1_b, nullptr, nullptr,
        nullptr, nullptr, nullptr, tt, nullptr, NG);
    gemm_mfma<false, false, 1, 0, true, true, false><<<GB, 256, 0, stream>>>(
        tt, p2_t, plin2_b, nullptr, nullptr,
        hh, pln2_g, pln2_b, out, nullptr, NG);
}

// Round 9
// 662.337 us; speedup vs baseline: 1.2755x; 1.2755x over previous
//
#include <hip/hip_runtime.h>
#include <math.h>

#define NN 100000
#define NE 1600000
#define NG 1024
#define FF 128
#define BSH 9
#define NBK ((NN + 511) >> BSH)   // 196 buckets of 512 nodes
#define RB 256                    // radix blocks

typedef __attribute__((ext_vector_type(8))) short short8;
typedef __attribute__((ext_vector_type(4))) float f32x4;

__device__ __forceinline__ unsigned short f2b(float f) {
    union { float f; unsigned u; } v; v.f = f;
    unsigned r = (v.u + 0x7FFF + ((v.u >> 16) & 1)) >> 16;
    return (unsigned short)r;
}
__device__ __forceinline__ float us2f(unsigned short u) {
    union { unsigned u; float f; } v; v.u = ((unsigned)u) << 16; return v.f;
}
__device__ __forceinline__ float b2f_lo(unsigned u) {
    union { unsigned u; float f; } v; v.u = u << 16; return v.f;
}
__device__ __forceinline__ float b2f_hi(unsigned u) {
    union { unsigned u; float f; } v; v.u = u & 0xFFFF0000u; return v.f;
}

// ---------------- radix pass 1: LDS-aggregated bucket histogram -------------
__global__ __launch_bounds__(256)
void radix_hist(const int* __restrict__ dst, int* __restrict__ bcnt, int n) {
    __shared__ int cnt[NBK];
    for (int i = threadIdx.x; i < NBK; i += 256) cnt[i] = 0;
    __syncthreads();
    const int per = (n + RB - 1) / RB;
    const int beg = blockIdx.x * per;
    const int end = min(n, beg + per);
    for (int i = beg + threadIdx.x; i < end; i += 256)
        atomicAdd(&cnt[dst[i] >> BSH], 1);
    __syncthreads();
    for (int i = threadIdx.x; i < NBK; i += 256)
        if (cnt[i]) atomicAdd(&bcnt[i], cnt[i]);
}

// ---------------- radix pass 2: scatter packed (src<<9|local) into buckets --
__global__ __launch_bounds__(256)
void radix_scatter(const int* __restrict__ src, const int* __restrict__ dst,
                   int* __restrict__ bcur, unsigned* __restrict__ pairs, int n) {
    __shared__ int base[NBK];
    __shared__ int cnt[NBK];
    for (int i = threadIdx.x; i < NBK; i += 256) cnt[i] = 0;
    __syncthreads();
    const int per = (n + RB - 1) / RB;
    const int beg = blockIdx.x * per;
    const int end = min(n, beg + per);
    for (int i = beg + threadIdx.x; i < end; i += 256)
        atomicAdd(&cnt[dst[i] >> BSH], 1);
    __syncthreads();
    for (int i = threadIdx.x; i < NBK; i += 256)
        base[i] = cnt[i] ? atomicAdd(&bcur[i], cnt[i]) : 0;
    __syncthreads();
    for (int i = beg + threadIdx.x; i < end; i += 256) {
        int d = dst[i];
        int p = atomicAdd(&base[d >> BSH], 1);
        pairs[p] = ((unsigned)src[i] << BSH) | (unsigned)(d & 511);
    }
}

// ---------------- radix pass 3: per-bucket hist+scan+scatter -> CSR ---------
__global__ __launch_bounds__(256)
void bucket_build(const unsigned* __restrict__ pairs, const int* __restrict__ boff,
                  int* __restrict__ row_off, float* __restrict__ inv_deg,
                  int* __restrict__ ssrc) {
    __shared__ int cnt[512];
    __shared__ int curs[512];
    __shared__ int wsum[4];
    const int b = blockIdx.x;
    const int n0 = b << BSH;
    const int t = threadIdx.x;
    const int lane = t & 63, wid = t >> 6;

    for (int i = t; i < 512; i += 256) cnt[i] = 0;
    __syncthreads();
    const int beg = boff[b], end = boff[b + 1];
    for (int i = beg + t; i < end; i += 256)
        atomicAdd(&cnt[pairs[i] & 511], 1);
    __syncthreads();

    int c0 = cnt[2 * t], c1 = cnt[2 * t + 1];
    int v = c0 + c1;
    int x = v;
    #pragma unroll
    for (int o = 1; o < 64; o <<= 1) {
        int y = __shfl_up(x, o);
        if (lane >= o) x += y;
    }
    if (lane == 63) wsum[wid] = x;
    __syncthreads();
    if (t == 0) {
        int s = 0;
        #pragma unroll
        for (int w2 = 0; w2 < 4; ++w2) { int tv = wsum[w2]; wsum[w2] = s; s += tv; }
    }
    __syncthreads();
    int g0 = beg + wsum[wid] + x - v;
    int g1 = g0 + c0;
    curs[2 * t] = g0;
    curs[2 * t + 1] = g1;
    {
        int node = n0 + 2 * t;
        if (node < NN) { row_off[node] = g0; inv_deg[node] = 1.0f / (float)(c0 > 1 ? c0 : 1); }
        node = n0 + 2 * t + 1;
        if (node < NN) { row_off[node] = g1; inv_deg[node] = 1.0f / (float)(c1 > 1 ? c1 : 1); }
    }
    __syncthreads();
    for (int i = beg + t; i < end; i += 256) {
        unsigned pr = pairs[i];
        int p = atomicAdd(&curs[pr & 511], 1);
        ssrc[p] = (int)(pr >> BSH);
    }
    if (b == 0 && t == 0) row_off[NN] = boff[NBK];
}

// ---------------- graph offsets via binary search on sorted batch -----------
__global__ __launch_bounds__(256)
void graph_offsets(const int* __restrict__ batch, int* __restrict__ g_off,
                   float* __restrict__ inv_cnt) {
    int g = blockIdx.x * blockDim.x + threadIdx.x;
    if (g > NG) return;
    if (g == NG) { g_off[NG] = NN; return; }
    int lo = 0, hi = NN;
    while (lo < hi) { int mid = (lo + hi) >> 1; if (batch[mid] < g) lo = mid + 1; else hi = mid; }
    int lo2 = lo, hi2 = NN;
    while (lo2 < hi2) { int mid = (lo2 + hi2) >> 1; if (batch[mid] < g + 1) lo2 = mid + 1; else hi2 = mid; }
    g_off[g] = lo;
    int c = lo2 - lo;
    inv_cnt[g] = 1.0f / (float)(c > 1 ? c : 1);
}

// ---------------- exclusive scan (only for 196 bucket counts) ---------------
__global__ __launch_bounds__(1024)
void scan_hist(const int* __restrict__ in, int* __restrict__ off_out,
               int* __restrict__ cur_out, int n) {
    __shared__ int wsum[16];
    __shared__ int carry_s;
    const int t = threadIdx.x, lane = t & 63, wid = t >> 6;
    if (t == 0) carry_s = 0;
    __syncthreads();
    for (int base = 0; base < n; base += 1024) {
        int i = base + t;
        int v = (i < n) ? in[i] : 0;
        int x = v;
        #pragma unroll
        for (int o = 1; o < 64; o <<= 1) {
            int y = __shfl_up(x, o);
            if (lane >= o) x += y;
        }
        if (lane == 63) wsum[wid] = x;
        __syncthreads();
        if (t == 0) {
            int s = carry_s;
            #pragma unroll
            for (int w2 = 0; w2 < 16; ++w2) { int tv = wsum[w2]; wsum[w2] = s; s += tv; }
            carry_s = s;
        }
        __syncthreads();
        int excl = wsum[wid] + x - v;
        if (i < n) {
            off_out[i] = excl;
            if (cur_out) cur_out[i] = excl;
        }
        __syncthreads();
    }
    if (t == 0) off_out[n] = carry_s;
}

// ---------------- weight prep: fp32 [k][n] -> bf16 MFMA-FRAGMENT order ------
// frag idx = ((kc*8+nt)*64 + lane)*8 + j  with n = nt*16+(lane&15),
// k = kc*32 + (lane>>4)*8 + j.  A wave's B-read for (kc,nt) is then a
// contiguous 1 KB at lane*16B -> conflict-free LDS / coalesced global.
struct WTab { const float* a[16]; };
__global__ __launch_bounds__(256)
void prep_weights(WTab tab, unsigned short* __restrict__ dst) {
    int w = blockIdx.x >> 6;
    int idx = ((blockIdx.x & 63) << 8) + threadIdx.x;
    int j = idx & 7, lane = (idx >> 3) & 63, nt = (idx >> 9) & 7, kc = idx >> 12;
    int cb = lane & 15, rq = lane >> 4;
    int k = kc * 32 + rq * 8 + j;
    int n = nt * 16 + cb;
    dst[(size_t)w * 16384 + idx] = f2b(tab.a[w][k * 128 + n]);
}

// ---------------- SAGE mean aggregation ----------------
__global__ __launch_bounds__(256)
void sage_agg(const unsigned short* __restrict__ hb, const int* __restrict__ row_off,
              const int* __restrict__ ssrc, const float* __restrict__ inv_deg,
              unsigned short* __restrict__ aggb) {
    const int wid = threadIdx.x >> 6;
    const int lane = threadIdx.x & 63;
    const int node = blockIdx.x * 4 + wid;
    const int eg = lane >> 4, j = lane & 15;
    const int beg = row_off[node], end = row_off[node + 1];
    float a[8] = {0.f, 0.f, 0.f, 0.f, 0.f, 0.f, 0.f, 0.f};
    int e = beg + eg;
    for (; e + 4 < end; e += 8) {
        int s0 = ssrc[e], s1 = ssrc[e + 4];
        uint4 v0 = *(const uint4*)&hb[(size_t)s0 * FF + j * 8];
        uint4 v1 = *(const uint4*)&hb[(size_t)s1 * FF + j * 8];
        a[0] += b2f_lo(v0.x) + b2f_lo(v1.x); a[1] += b2f_hi(v0.x) + b2f_hi(v1.x);
        a[2] += b2f_lo(v0.y) + b2f_lo(v1.y); a[3] += b2f_hi(v0.y) + b2f_hi(v1.y);
        a[4] += b2f_lo(v0.z) + b2f_lo(v1.z); a[5] += b2f_hi(v0.z) + b2f_hi(v1.z);
        a[6] += b2f_lo(v0.w) + b2f_lo(v1.w); a[7] += b2f_hi(v0.w) + b2f_hi(v1.w);
    }
    if (e < end) {
        int s0 = ssrc[e];
        uint4 v0 = *(const uint4*)&hb[(size_t)s0 * FF + j * 8];
        a[0] += b2f_lo(v0.x); a[1] += b2f_hi(v0.x);
        a[2] += b2f_lo(v0.y); a[3] += b2f_hi(v0.y);
        a[4] += b2f_lo(v0.z); a[5] += b2f_hi(v0.z);
        a[6] += b2f_lo(v0.w); a[7] += b2f_hi(v0.w);
    }
    #pragma unroll
    for (int k = 0; k < 8; ++k) {
        a[k] += __shfl_xor(a[k], 16);
        a[k] += __shfl_xor(a[k], 32);
    }
    if (eg == 0) {
        float id = inv_deg[node];
        uint4 o;
        o.x = (unsigned)f2b(a[0] * id) | ((unsigned)f2b(a[1] * id) << 16);
        o.y = (unsigned)f2b(a[2] * id) | ((unsigned)f2b(a[3] * id) << 16);
        o.z = (unsigned)f2b(a[4] * id) | ((unsigned)f2b(a[5] * id) << 16);
        o.w = (unsigned)f2b(a[6] * id) | ((unsigned)f2b(a[7] * id) << 16);
        *(uint4*)&aggb[(size_t)node * FF + j * 8] = o;
    }
}

// ---------------- mean pool per graph from bf16 ----------------
__global__ __launch_bounds__(128)
void pool_mean_b(const unsigned short* __restrict__ src, const int* __restrict__ g_off,
                 const float* __restrict__ inv_cnt, float* __restrict__ out) {
    const int g = blockIdx.x;
    const int j = threadIdx.x;
    const int beg = g_off[g], end = g_off[g + 1];
    float s = 0.f;
    for (int n = beg; n < end; ++n) s += us2f(src[(size_t)n * FF + j]);
    out[(size_t)g * FF + j] = s * inv_cnt[g];
}

// ---------------- MFMA bf16 GEMM, frag-ordered W from global ---------------
template<bool AB16, bool R1, int RESM, int ACT, bool LN, bool OF32, bool OB16>
__global__ __launch_bounds__(256)
void gemm_mfma(const void* __restrict__ A_,
               const unsigned short* __restrict__ Wf,
               const float* __restrict__ bias,
               const float* __restrict__ rvec, const float* __restrict__ rrow,
               const float* __restrict__ res,
               const float* __restrict__ lng, const float* __restrict__ lnb,
               float* __restrict__ outf, unsigned short* __restrict__ outb, int M) {
    __shared__ short Al[64 * 136];

    const int t = threadIdx.x;
    const int lane = t & 63, wid = t >> 6;
    const int m0 = blockIdx.x * 64;
    const int cb = lane & 15, rq = lane >> 4;

    if (AB16) {
        const unsigned short* Ab = (const unsigned short*)A_;
        for (int i = t; i < 1024; i += 256) {
            int row = i >> 4, seg = i & 15;
            int gr = m0 + row; if (gr >= M) gr = M - 1;
            *(uint4*)&Al[row * 136 + seg * 8] = *(const uint4*)&Ab[(size_t)gr * 128 + seg * 8];
        }
    } else {
        const float* Af = (const float*)A_;
        for (int i = t; i < 2048; i += 256) {
            int row = i >> 5, seg = i & 31;
            int gr = m0 + row; if (gr >= M) gr = M - 1;
            float4 v = *(const float4*)&Af[(size_t)gr * 128 + seg * 4];
            ushort4 o = {f2b(v.x), f2b(v.y), f2b(v.z), f2b(v.w)};
            *(ushort4*)&Al[row * 136 + seg * 4] = o;
        }
    }
    __syncthreads();

    f32x4 acc[8];
    #pragma unroll
    for (int nt = 0; nt < 8; ++nt) acc[nt] = (f32x4){0.f, 0.f, 0.f, 0.f};

    const int aoff_base = (wid * 16 + cb) * 136 + rq * 8;
    for (int kc = 0; kc < 4; ++kc) {
        short8 a0 = *(const short8*)&Al[aoff_base + kc * 32];
        #pragma unroll
        for (int nt = 0; nt < 8; ++nt) {
            short8 b0 = *(const short8*)&Wf[(size_t)(kc * 8 + nt) * 512 + lane * 8];
            acc[nt] = __builtin_amdgcn_mfma_f32_16x16x32_bf16(a0, b0, acc[nt], 0, 0, 0);
        }
    }

    float bs[8], rr[8], lg[8], lb[8];
    #pragma unroll
    for (int nt = 0; nt < 8; ++nt) {
        int col = nt * 16 + cb;
        bs[nt] = bias[col];
        if (R1) rr[nt] = rrow[col];
        if (LN) { lg[nt] = lng[col]; lb[nt] = lnb[col]; }
    }
    #pragma unroll
    for (int reg = 0; reg < 4; ++reg) {
        int m = m0 + wid * 16 + rq * 4 + reg;
        int mc = m < M ? m : M - 1;
        float v[8];
        #pragma unroll
        for (int nt = 0; nt < 8; ++nt) v[nt] = acc[nt][reg] + bs[nt];
        if (R1) {
            float rv = rvec[mc];
            #pragma unroll
            for (int nt = 0; nt < 8; ++nt) v[nt] += rv * rr[nt];
        }
        if (RESM == 1) {
            #pragma unroll
            for (int nt = 0; nt < 8; ++nt) v[nt] += res[(size_t)mc * 128 + nt * 16 + cb];
        }
        if (ACT == 1) {
            #pragma unroll
            for (int nt = 0; nt < 8; ++nt) v[nt] = v[nt] > 0.f ? v[nt] : expm1f(v[nt]);
        }
        if (LN) {
            float s1 = 0.f, s2 = 0.f;
            #pragma unroll
            for (int nt = 0; nt < 8; ++nt) { s1 += v[nt]; s2 += v[nt] * v[nt]; }
            #pragma unroll
            for (int o = 8; o >= 1; o >>= 1) { s1 += __shfl_xor(s1, o); s2 += __shfl_xor(s2, o); }
            float mu = s1 * (1.f / 128.f);
            float rs = rsqrtf(s2 * (1.f / 128.f) - mu * mu + 1e-5f);
            #pragma unroll
            for (int nt = 0; nt < 8; ++nt) v[nt] = (v[nt] - mu) * rs * lg[nt] + lb[nt];
        }
        if (m < M) {
            #pragma unroll
            for (int nt = 0; nt < 8; ++nt) {
                size_t o = (size_t)m * 128 + nt * 16 + cb;
                if (OF32) outf[o] = v[nt];
                if (OB16) outb[o] = f2b(v[nt]);
            }
        }
    }
}

// ---------------- fused GEMM chain, frag-W staged in LDS (7 barriers) -------
// Barriers protect ONLY the shared Wb buffer; all A-reads / epilogue writes
// are band-local to the owning wave.
__global__ __launch_bounds__(256)
void gc_chain(const unsigned short* __restrict__ hin, const unsigned short* __restrict__ aggb,
              unsigned short* __restrict__ hout,
              const unsigned short* __restrict__ Wl_f, const unsigned short* __restrict__ Wr_f,
              const unsigned short* __restrict__ W1_f, const unsigned short* __restrict__ W2_f,
              const float* __restrict__ bl,
              const float* __restrict__ g1, const float* __restrict__ b1,
              const float* __restrict__ bb1, const float* __restrict__ bb2,
              const float* __restrict__ g2, const float* __restrict__ b2, int M) {
    __shared__ short Hl[64 * 136];     // h tile -> y1 tile
    __shared__ short Gl[64 * 136];     // agg tile -> elu(t) tile
    __shared__ short Wb[16384];        // one full frag-ordered W (32 KB)

    const int t = threadIdx.x;
    const int lane = t & 63, wid = t >> 6;
    const int m0 = blockIdx.x * 64;
    const int cb = lane & 15, rq = lane >> 4;
    const int aoff_base = (wid * 16 + cb) * 136 + rq * 8;
    const int boff = lane * 8;

    // ---- stage Hl, Gl, Wl ----
    for (int i = t; i < 1024; i += 256) {
        int row = i >> 4, seg = i & 15;
        int gr = m0 + row; if (gr >= M) gr = M - 1;
        *(uint4*)&Hl[row * 136 + seg * 8] = *(const uint4*)&hin[(size_t)gr * 128 + seg * 8];
        *(uint4*)&Gl[row * 136 + seg * 8] = *(const uint4*)&aggb[(size_t)gr * 128 + seg * 8];
    }
    for (int i = t; i < 2048; i += 256)
        ((uint4*)Wb)[i] = ((const uint4*)Wl_f)[i];
    __syncthreads();

    f32x4 acc[8];
    #pragma unroll
    for (int nt = 0; nt < 8; ++nt) acc[nt] = (f32x4){0.f, 0.f, 0.f, 0.f};

    // ---- dual GEMM part 1: acc = agg@Wl ----
    for (int kc = 0; kc < 4; ++kc) {
        short8 a0 = *(const short8*)&Gl[aoff_base + kc * 32];
        #pragma unroll
        for (int nt = 0; nt < 8; ++nt)
            acc[nt] = __builtin_amdgcn_mfma_f32_16x16x32_bf16(
                a0, *(const short8*)&Wb[(kc * 8 + nt) * 512 + boff], acc[nt], 0, 0, 0);
    }
    __syncthreads();
    for (int i = t; i < 2048; i += 256)
        ((uint4*)Wb)[i] = ((const uint4*)Wr_f)[i];
    __syncthreads();
    // ---- dual GEMM part 2: acc += h@Wr ----
    for (int kc = 0; kc < 4; ++kc) {
        short8 a1 = *(const short8*)&Hl[aoff_base + kc * 32];
        #pragma unroll
        for (int nt = 0; nt < 8; ++nt)
            acc[nt] = __builtin_amdgcn_mfma_f32_16x16x32_bf16(
                a1, *(const short8*)&Wb[(kc * 8 + nt) * 512 + boff], acc[nt], 0, 0, 0);
    }

    // ---- epilogue 1 (band-local): y1 = LN1(acc + bl + h) -> Hl + regs ----
    float y1r[4][8];
    {
        float bs[8], lg[8], lb[8];
        #pragma unroll
        for (int nt = 0; nt < 8; ++nt) {
            int col = nt * 16 + cb;
            bs[nt] = bl[col]; lg[nt] = g1[col]; lb[nt] = b1[col];
        }
        #pragma unroll
        for (int reg = 0; reg < 4; ++reg) {
            int r = wid * 16 + rq * 4 + reg;
            float v[8];
            float s1 = 0.f, s2 = 0.f;
            #pragma unroll
            for (int nt = 0; nt < 8; ++nt) {
                v[nt] = acc[nt][reg] + bs[nt] + us2f((unsigned short)Hl[r * 136 + nt * 16 + cb]);
                s1 += v[nt]; s2 += v[nt] * v[nt];
            }
            #pragma unroll
            for (int o = 8; o >= 1; o >>= 1) { s1 += __shfl_xor(s1, o); s2 += __shfl_xor(s2, o); }
            float mu = s1 * (1.f / 128.f);
            float rs = rsqrtf(s2 * (1.f / 128.f) - mu * mu + 1e-5f);
            #pragma unroll
            for (int nt = 0; nt < 8; ++nt) {
                float y = (v[nt] - mu) * rs * lg[nt] + lb[nt];
                y1r[reg][nt] = y;
                Hl[r * 136 + nt * 16 + cb] = (short)f2b(y);
            }
        }
    }
    __syncthreads();
    for (int i = t; i < 2048; i += 256)
        ((uint4*)Wb)[i] = ((const uint4*)W1_f)[i];
    __syncthreads();

    // ---- FF1: t = elu(y1@W1 + bb1) -> Gl (band-local) ----
    #pragma unroll
    for (int nt = 0; nt < 8; ++nt) acc[nt] = (f32x4){0.f, 0.f, 0.f, 0.f};
    for (int kc = 0; kc < 4; ++kc) {
        short8 a0 = *(const short8*)&Hl[aoff_base + kc * 32];
        #pragma unroll
        for (int nt = 0; nt < 8; ++nt)
            acc[nt] = __builtin_amdgcn_mfma_f32_16x16x32_bf16(
                a0, *(const short8*)&Wb[(kc * 8 + nt) * 512 + boff], acc[nt], 0, 0, 0);
    }
    {
        float bs[8];
        #pragma unroll
        for (int nt = 0; nt < 8; ++nt) bs[nt] = bb1[nt * 16 + cb];
        #pragma unroll
        for (int reg = 0; reg < 4; ++reg) {
            int r = wid * 16 + rq * 4 + reg;
            #pragma unroll
            for (int nt = 0; nt < 8; ++nt) {
                float v = acc[nt][reg] + bs[nt];
                v = v > 0.f ? v : expm1f(v);
                Gl[r * 136 + nt * 16 + cb] = (short)f2b(v);
            }
        }
    }
    __syncthreads();
    for (int i = t; i < 2048; i += 256)
        ((uint4*)Wb)[i] = ((const uint4*)W2_f)[i];
    __syncthreads();

    // ---- FF2: h' = LN2(t@W2 + bb2 + y1) -> global ----
    #pragma unroll
    for (int nt = 0; nt < 8; ++nt) acc[nt] = (f32x4){0.f, 0.f, 0.f, 0.f};
    for (int kc = 0; kc < 4; ++kc) {
        short8 a0 = *(const short8*)&Gl[aoff_base + kc * 32];
        #pragma unroll
        for (int nt = 0; nt < 8; ++nt)
            acc[nt] = __builtin_amdgcn_mfma_f32_16x16x32_bf16(
                a0, *(const short8*)&Wb[(kc * 8 + nt) * 512 + boff], acc[nt], 0, 0, 0);
    }
    {
        float bs[8], lg[8], lb[8];
        #pragma unroll
        for (int nt = 0; nt < 8; ++nt) {
            int col = nt * 16 + cb;
            bs[nt] = bb2[col]; lg[nt] = g2[col]; lb[nt] = b2[col];
        }
        #pragma unroll
        for (int reg = 0; reg < 4; ++reg) {
            int r = wid * 16 + rq * 4 + reg;
            int m = m0 + r;
            float v[8];
            float s1 = 0.f, s2 = 0.f;
            #pragma unroll
            for (int nt = 0; nt < 8; ++nt) {
                v[nt] = acc[nt][reg] + bs[nt] + y1r[reg][nt];
                s1 += v[nt]; s2 += v[nt] * v[nt];
            }
            #pragma unroll
            for (int o = 8; o >= 1; o >>= 1) { s1 += __shfl_xor(s1, o); s2 += __shfl_xor(s2, o); }
            float mu = s1 * (1.f / 128.f);
            float rs = rsqrtf(s2 * (1.f / 128.f) - mu * mu + 1e-5f);
            if (m < M) {
                #pragma unroll
                for (int nt = 0; nt < 8; ++nt)
                    hout[(size_t)m * 128 + nt * 16 + cb] = f2b((v[nt] - mu) * rs * lg[nt] + lb[nt]);
            }
        }
    }
}

extern "C" void kernel_launch(void* const* d_in, const int* in_sizes, int n_in,
                              void* d_out, int out_size, void* d_ws, size_t ws_size,
                              hipStream_t stream) {
    const float* x      = (const float*)d_in[0];
    const float* w      = (const float*)d_in[1];
    const int*   ei     = (const int*)d_in[2];
    const int*   batch  = (const int*)d_in[3];
    const float* W_in   = (const float*)d_in[4];
    const float* b_in   = (const float*)d_in[5];
    const float* sage_Wl = (const float*)d_in[6];
    const float* sage_bl = (const float*)d_in[7];
    const float* sage_Wr = (const float*)d_in[8];
    const float* ln1_g  = (const float*)d_in[9];
    const float* ln1_b  = (const float*)d_in[10];
    const float* lin1_W = (const float*)d_in[11];
    const float* lin1_b = (const float*)d_in[12];
    const float* lin2_W = (const float*)d_in[13];
    const float* lin2_b = (const float*)d_in[14];
    const float* ln2_g  = (const float*)d_in[15];
    const float* ln2_b  = (const float*)d_in[16];
    const float* mdf_W  = (const float*)d_in[17];
    const float* mdf_b  = (const float*)d_in[18];
    const float* pln1_g = (const float*)d_in[19];
    const float* pln1_b = (const float*)d_in[20];
    const float* plin1_W = (const float*)d_in[21];
    const float* plin1_b = (const float*)d_in[22];
    const float* plin2_W = (const float*)d_in[23];
    const float* plin2_b = (const float*)d_in[24];
    const float* pln2_g = (const float*)d_in[25];
    const float* pln2_b = (const float*)d_in[26];
    float* out = (float*)d_out;

    const int* e_src = ei;
    const int* e_dst = ei + NE;

    // ---- workspace layout ----
    float* ws = (float*)d_ws;
    size_t off = 0;
    float* gm    = ws + off; off += (size_t)NG * FF;
    float* hh    = ws + off; off += (size_t)NG * FF;
    float* tt    = ws + off; off += (size_t)NG * FF;
    float* inv_deg = ws + off; off += NN;
    float* inv_cnt = ws + off; off += NG;
    unsigned short* us = (unsigned short*)(ws + off);
    size_t uoff = 0;
    unsigned short* hb0  = us + uoff; uoff += (size_t)NN * FF;
    unsigned short* hb1  = us + uoff; uoff += (size_t)NN * FF;
    unsigned short* aggb = us + uoff; uoff += (size_t)NN * FF;
    unsigned short* wt   = us + uoff; uoff += (size_t)16 * 16384;
    int* iw = (int*)(us + uoff);
    size_t ioff = 0;
    unsigned* pairs = (unsigned*)iw; ioff += NE;
    int* ssrc    = iw + ioff; ioff += NE;
    int* row_off = iw + ioff; ioff += NN + 1;
    int* g_off   = iw + ioff; ioff += NG + 1;
    int* bcnt    = iw + ioff; ioff += NBK;
    int* boff    = iw + ioff; ioff += NBK + 1;
    int* bcur    = iw + ioff; ioff += NBK;

    // ---- weight prep (16 matrices -> frag-ordered bf16) ----
    WTab tab;
    tab.a[0] = W_in;
    for (int l = 0; l < 3; ++l) {
        tab.a[1 + l]  = sage_Wl + (size_t)l * 16384;
        tab.a[4 + l]  = sage_Wr + (size_t)l * 16384;
        tab.a[7 + l]  = lin1_W + (size_t)l * 16384;
        tab.a[10 + l] = lin2_W + (size_t)l * 16384;
    }
    tab.a[13] = mdf_W;      // first 128 rows only (Wa)
    tab.a[14] = plin1_W;
    tab.a[15] = plin2_W;
    prep_weights<<<16 * 64, 256, 0, stream>>>(tab, wt);
    const unsigned short* win_t = wt + 0 * 16384;
    const unsigned short* wa_t  = wt + 13 * 16384;
    const unsigned short* p1_t  = wt + 14 * 16384;
    const unsigned short* p2_t  = wt + 15 * 16384;

    // ---- build CSR (LDS-aggregated radix partition, no global scan) ----
    hipMemsetAsync(bcnt, 0, sizeof(int) * NBK, stream);
    radix_hist<<<RB, 256, 0, stream>>>(e_dst, bcnt, NE);
    scan_hist<<<1, 1024, 0, stream>>>(bcnt, boff, bcur, NBK);
    graph_offsets<<<(NG + 256) / 256, 256, 0, stream>>>(batch, g_off, inv_cnt);
    radix_scatter<<<RB, 256, 0, stream>>>(e_src, e_dst, bcur, pairs, NE);
    bucket_build<<<NBK, 256, 0, stream>>>(pairs, boff, row_off, inv_deg, ssrc);

    const int GN = (NN + 63) / 64;     // 1563
    const int GB = NG / 64;            // 16

    // ---- input linear: hb0 = bf16(x @ W_in[0:128] + w * W_in[128] + b_in) ----
    gemm_mfma<false, true, 0, 0, false, false, true><<<GN, 256, 0, stream>>>(
        x, win_t, b_in, w, W_in + 128 * 128,
        nullptr, nullptr, nullptr, nullptr, hb0, NN);

    // ---- 3 GC blocks: gather (high-occupancy) + fused GEMM chain ----
    unsigned short* hcur = hb0;
    unsigned short* hnxt = hb1;
    for (int l = 0; l < 3; ++l) {
        sage_agg<<<NN / 4, 256, 0, stream>>>(hcur, row_off, ssrc, inv_deg, aggb);
        gc_chain<<<GN, 256, 0, stream>>>(
            hcur, aggb, hnxt,
            wt + (size_t)(1 + l) * 16384, wt + (size_t)(4 + l) * 16384,
            wt + (size_t)(7 + l) * 16384, wt + (size_t)(10 + l) * 16384,
            sage_bl + (size_t)l * FF,
            ln1_g + (size_t)l * FF, ln1_b + (size_t)l * FF,
            lin1_b + (size_t)l * FF, lin2_b + (size_t)l * FF,
            ln2_g + (size_t)l * FF, ln2_b + (size_t)l * FF, NN);
        unsigned short* tmp = hcur; hcur = hnxt; hnxt = tmp;
    }

    // ---- head: pool(h2) == gm @ mdf_W[0:128] + mdf_b  (exact algebra) ----
    pool_mean_b<<<NG, 128, 0, stream>>>(hcur, g_off, inv_cnt, gm);
    gemm_mfma<false, false, 0, 0, true, true, false><<<GB, 256, 0, stream>>>(
        gm, wa_t, mdf_b, nullptr, nullptr,
        nullptr, pln1_g, pln1_b, hh, nullptr, NG);
    gemm_mfma<false, false, 0, 1, false, true, false><<<GB, 256, 0, stream>>>(
        hh, p1_t, plin1_b, nullptr, nullptr,
        nullptr, nullptr, nullptr, tt, nullptr, NG);
    gemm_mfma<false, false, 1, 0, true, true, false><<<GB, 256, 0, stream>>>(
        tt, p2_t, plin2_b, nullptr, nullptr,
        hh, pln2_g, pln2_b, out, nullptr, NG);
}

// Round 10
// 650.783 us; speedup vs baseline: 1.2981x; 1.0178x over previous
//
#include <hip/hip_runtime.h>
#include <math.h>

#define NN 100000
#define NE 1600000
#define NG 1024
#define FF 128
#define BSH 9
#define NBK ((NN + 511) >> BSH)   // 196 buckets of 512 nodes
#define RB 256                    // radix blocks
#define BCAP 16384                // fixed bucket capacity (mean 8192, sigma~90)

typedef __attribute__((ext_vector_type(8))) short short8;
typedef __attribute__((ext_vector_type(4))) float f32x4;

__device__ __forceinline__ unsigned short f2b(float f) {
    union { float f; unsigned u; } v; v.f = f;
    unsigned r = (v.u + 0x7FFF + ((v.u >> 16) & 1)) >> 16;
    return (unsigned short)r;
}
__device__ __forceinline__ float us2f(unsigned short u) {
    union { unsigned u; float f; } v; v.u = ((unsigned)u) << 16; return v.f;
}
__device__ __forceinline__ float b2f_lo(unsigned u) {
    union { unsigned u; float f; } v; v.u = u << 16; return v.f;
}
__device__ __forceinline__ float b2f_hi(unsigned u) {
    union { unsigned u; float f; } v; v.u = u & 0xFFFF0000u; return v.f;
}

// ---------------- init bucket cursors to region bases -----------------------
__global__ void init_bcur(int* __restrict__ bcur) {
    int b = blockIdx.x * blockDim.x + threadIdx.x;
    if (b < NBK) bcur[b] = b * BCAP;
}

// ---------------- pass 1: scatter packed (src<<9|local) into padded buckets -
__global__ __launch_bounds__(256)
void radix_scatter(const int* __restrict__ src, const int* __restrict__ dst,
                   int* __restrict__ bcur, unsigned* __restrict__ pairs, int n) {
    __shared__ int base[NBK];
    __shared__ int cnt[NBK];
    for (int i = threadIdx.x; i < NBK; i += 256) cnt[i] = 0;
    __syncthreads();
    const int per = (n + RB - 1) / RB;
    const int beg = blockIdx.x * per;
    const int end = min(n, beg + per);
    for (int i = beg + threadIdx.x; i < end; i += 256)
        atomicAdd(&cnt[dst[i] >> BSH], 1);
    __syncthreads();
    for (int i = threadIdx.x; i < NBK; i += 256)
        base[i] = cnt[i] ? atomicAdd(&bcur[i], cnt[i]) : 0;
    __syncthreads();
    for (int i = beg + threadIdx.x; i < end; i += 256) {
        int d = dst[i];
        int p = atomicAdd(&base[d >> BSH], 1);
        pairs[p] = ((unsigned)src[i] << BSH) | (unsigned)(d & 511);
    }
}

// ---------------- pass 2: per-bucket hist+scan+scatter -> padded CSR --------
__global__ __launch_bounds__(256)
void bucket_build(const unsigned* __restrict__ pairs, const int* __restrict__ bcur,
                  int* __restrict__ row_beg, int* __restrict__ row_end,
                  float* __restrict__ inv_deg, int* __restrict__ ssrc) {
    __shared__ int cnt[512];
    __shared__ int curs[512];
    __shared__ int wsum[4];
    const int b = blockIdx.x;
    const int n0 = b << BSH;
    const int t = threadIdx.x;
    const int lane = t & 63, wid = t >> 6;

    for (int i = t; i < 512; i += 256) cnt[i] = 0;
    __syncthreads();
    const int beg = b * BCAP, end = bcur[b];
    for (int i = beg + t; i < end; i += 256)
        atomicAdd(&cnt[pairs[i] & 511], 1);
    __syncthreads();

    int c0 = cnt[2 * t], c1 = cnt[2 * t + 1];
    int v = c0 + c1;
    int x = v;
    #pragma unroll
    for (int o = 1; o < 64; o <<= 1) {
        int y = __shfl_up(x, o);
        if (lane >= o) x += y;
    }
    if (lane == 63) wsum[wid] = x;
    __syncthreads();
    if (t == 0) {
        int s = 0;
        #pragma unroll
        for (int w2 = 0; w2 < 4; ++w2) { int tv = wsum[w2]; wsum[w2] = s; s += tv; }
    }
    __syncthreads();
    int g0 = beg + wsum[wid] + x - v;
    int g1 = g0 + c0;
    curs[2 * t] = g0;
    curs[2 * t + 1] = g1;
    {
        int node = n0 + 2 * t;
        if (node < NN) {
            row_beg[node] = g0; row_end[node] = g1;
            inv_deg[node] = 1.0f / (float)(c0 > 1 ? c0 : 1);
        }
        node = n0 + 2 * t + 1;
        if (node < NN) {
            row_beg[node] = g1; row_end[node] = g1 + c1;
            inv_deg[node] = 1.0f / (float)(c1 > 1 ? c1 : 1);
        }
    }
    __syncthreads();
    for (int i = beg + t; i < end; i += 256) {
        unsigned pr = pairs[i];
        int p = atomicAdd(&curs[pr & 511], 1);
        ssrc[p] = (int)(pr >> BSH);
    }
}

// ---------------- graph offsets via binary search on sorted batch -----------
__global__ __launch_bounds__(256)
void graph_offsets(const int* __restrict__ batch, int* __restrict__ g_off,
                   float* __restrict__ inv_cnt) {
    int g = blockIdx.x * blockDim.x + threadIdx.x;
    if (g > NG) return;
    if (g == NG) { g_off[NG] = NN; return; }
    int lo = 0, hi = NN;
    while (lo < hi) { int mid = (lo + hi) >> 1; if (batch[mid] < g) lo = mid + 1; else hi = mid; }
    int lo2 = lo, hi2 = NN;
    while (lo2 < hi2) { int mid = (lo2 + hi2) >> 1; if (batch[mid] < g + 1) lo2 = mid + 1; else hi2 = mid; }
    g_off[g] = lo;
    int c = lo2 - lo;
    inv_cnt[g] = 1.0f / (float)(c > 1 ? c : 1);
}

// ---------------- weight prep: fp32 [k][n] -> bf16 MFMA-FRAGMENT order ------
// frag idx = ((kc*8+nt)*64 + lane)*8 + j ; n = nt*16+(lane&15),
// k = kc*32+(lane>>4)*8+j.  Wave B-read for (kc,nt) = contiguous 1 KB.
struct WTab { const float* a[16]; };
__global__ __launch_bounds__(256)
void prep_weights(WTab tab, unsigned short* __restrict__ dst) {
    int w = blockIdx.x >> 6;
    int idx = ((blockIdx.x & 63) << 8) + threadIdx.x;
    int j = idx & 7, lane = (idx >> 3) & 63, nt = (idx >> 9) & 7, kc = idx >> 12;
    int cb = lane & 15, rq = lane >> 4;
    int k = kc * 32 + rq * 8 + j;
    int n = nt * 16 + cb;
    dst[(size_t)w * 16384 + idx] = f2b(tab.a[w][k * 128 + n]);
}

// ---------------- SAGE mean aggregation ----------------
__global__ __launch_bounds__(256)
void sage_agg(const unsigned short* __restrict__ hb, const int* __restrict__ row_beg,
              const int* __restrict__ row_end, const float* __restrict__ inv_deg,
              const int* __restrict__ ssrc, unsigned short* __restrict__ aggb) {
    const int wid = threadIdx.x >> 6;
    const int lane = threadIdx.x & 63;
    const int node = blockIdx.x * 4 + wid;
    const int eg = lane >> 4, j = lane & 15;
    const int beg = row_beg[node], end = row_end[node];
    float a[8] = {0.f, 0.f, 0.f, 0.f, 0.f, 0.f, 0.f, 0.f};
    int e = beg + eg;
    for (; e + 4 < end; e += 8) {
        int s0 = ssrc[e], s1 = ssrc[e + 4];
        uint4 v0 = *(const uint4*)&hb[(size_t)s0 * FF + j * 8];
        uint4 v1 = *(const uint4*)&hb[(size_t)s1 * FF + j * 8];
        a[0] += b2f_lo(v0.x) + b2f_lo(v1.x); a[1] += b2f_hi(v0.x) + b2f_hi(v1.x);
        a[2] += b2f_lo(v0.y) + b2f_lo(v1.y); a[3] += b2f_hi(v0.y) + b2f_hi(v1.y);
        a[4] += b2f_lo(v0.z) + b2f_lo(v1.z); a[5] += b2f_hi(v0.z) + b2f_hi(v1.z);
        a[6] += b2f_lo(v0.w) + b2f_lo(v1.w); a[7] += b2f_hi(v0.w) + b2f_hi(v1.w);
    }
    if (e < end) {
        int s0 = ssrc[e];
        uint4 v0 = *(const uint4*)&hb[(size_t)s0 * FF + j * 8];
        a[0] += b2f_lo(v0.x); a[1] += b2f_hi(v0.x);
        a[2] += b2f_lo(v0.y); a[3] += b2f_hi(v0.y);
        a[4] += b2f_lo(v0.z); a[5] += b2f_hi(v0.z);
        a[6] += b2f_lo(v0.w); a[7] += b2f_hi(v0.w);
    }
    #pragma unroll
    for (int k = 0; k < 8; ++k) {
        a[k] += __shfl_xor(a[k], 16);
        a[k] += __shfl_xor(a[k], 32);
    }
    if (eg == 0) {
        float id = inv_deg[node];
        uint4 o;
        o.x = (unsigned)f2b(a[0] * id) | ((unsigned)f2b(a[1] * id) << 16);
        o.y = (unsigned)f2b(a[2] * id) | ((unsigned)f2b(a[3] * id) << 16);
        o.z = (unsigned)f2b(a[4] * id) | ((unsigned)f2b(a[5] * id) << 16);
        o.w = (unsigned)f2b(a[6] * id) | ((unsigned)f2b(a[7] * id) << 16);
        *(uint4*)&aggb[(size_t)node * FF + j * 8] = o;
    }
}

// ---------------- mean pool per graph from bf16 ----------------
__global__ __launch_bounds__(128)
void pool_mean_b(const unsigned short* __restrict__ src, const int* __restrict__ g_off,
                 const float* __restrict__ inv_cnt, float* __restrict__ out) {
    const int g = blockIdx.x;
    const int j = threadIdx.x;
    const int beg = g_off[g], end = g_off[g + 1];
    float s = 0.f;
    for (int n = beg; n < end; ++n) s += us2f(src[(size_t)n * FF + j]);
    out[(size_t)g * FF + j] = s * inv_cnt[g];
}

// ---------------- MFMA bf16 GEMM, frag-ordered W from global ---------------
template<bool AB16, bool R1, int RESM, int ACT, bool LN, bool OF32, bool OB16>
__global__ __launch_bounds__(256)
void gemm_mfma(const void* __restrict__ A_,
               const unsigned short* __restrict__ Wf,
               const float* __restrict__ bias,
               const float* __restrict__ rvec, const float* __restrict__ rrow,
               const float* __restrict__ res,
               const float* __restrict__ lng, const float* __restrict__ lnb,
               float* __restrict__ outf, unsigned short* __restrict__ outb, int M) {
    __shared__ short Al[64 * 136];

    const int t = threadIdx.x;
    const int lane = t & 63, wid = t >> 6;
    const int m0 = blockIdx.x * 64;
    const int cb = lane & 15, rq = lane >> 4;

    if (AB16) {
        const unsigned short* Ab = (const unsigned short*)A_;
        for (int i = t; i < 1024; i += 256) {
            int row = i >> 4, seg = i & 15;
            int gr = m0 + row; if (gr >= M) gr = M - 1;
            *(uint4*)&Al[row * 136 + seg * 8] = *(const uint4*)&Ab[(size_t)gr * 128 + seg * 8];
        }
    } else {
        const float* Af = (const float*)A_;
        for (int i = t; i < 2048; i += 256) {
            int row = i >> 5, seg = i & 31;
            int gr = m0 + row; if (gr >= M) gr = M - 1;
            float4 v = *(const float4*)&Af[(size_t)gr * 128 + seg * 4];
            ushort4 o = {f2b(v.x), f2b(v.y), f2b(v.z), f2b(v.w)};
            *(ushort4*)&Al[row * 136 + seg * 4] = o;
        }
    }
    __syncthreads();

    f32x4 acc[8];
    #pragma unroll
    for (int nt = 0; nt < 8; ++nt) acc[nt] = (f32x4){0.f, 0.f, 0.f, 0.f};

    const int aoff_base = (wid * 16 + cb) * 136 + rq * 8;
    for (int kc = 0; kc < 4; ++kc) {
        short8 a0 = *(const short8*)&Al[aoff_base + kc * 32];
        #pragma unroll
        for (int nt = 0; nt < 8; ++nt) {
            short8 b0 = *(const short8*)&Wf[(size_t)(kc * 8 + nt) * 512 + lane * 8];
            acc[nt] = __builtin_amdgcn_mfma_f32_16x16x32_bf16(a0, b0, acc[nt], 0, 0, 0);
        }
    }

    float bs[8], rr[8], lg[8], lb[8];
    #pragma unroll
    for (int nt = 0; nt < 8; ++nt) {
        int col = nt * 16 + cb;
        bs[nt] = bias[col];
        if (R1) rr[nt] = rrow[col];
        if (LN) { lg[nt] = lng[col]; lb[nt] = lnb[col]; }
    }
    #pragma unroll
    for (int reg = 0; reg < 4; ++reg) {
        int m = m0 + wid * 16 + rq * 4 + reg;
        int mc = m < M ? m : M - 1;
        float v[8];
        #pragma unroll
        for (int nt = 0; nt < 8; ++nt) v[nt] = acc[nt][reg] + bs[nt];
        if (R1) {
            float rv = rvec[mc];
            #pragma unroll
            for (int nt = 0; nt < 8; ++nt) v[nt] += rv * rr[nt];
        }
        if (RESM == 1) {
            #pragma unroll
            for (int nt = 0; nt < 8; ++nt) v[nt] += res[(size_t)mc * 128 + nt * 16 + cb];
        }
        if (ACT == 1) {
            #pragma unroll
            for (int nt = 0; nt < 8; ++nt) v[nt] = v[nt] > 0.f ? v[nt] : expm1f(v[nt]);
        }
        if (LN) {
            float s1 = 0.f, s2 = 0.f;
            #pragma unroll
            for (int nt = 0; nt < 8; ++nt) { s1 += v[nt]; s2 += v[nt] * v[nt]; }
            #pragma unroll
            for (int o = 8; o >= 1; o >>= 1) { s1 += __shfl_xor(s1, o); s2 += __shfl_xor(s2, o); }
            float mu = s1 * (1.f / 128.f);
            float rs = rsqrtf(s2 * (1.f / 128.f) - mu * mu + 1e-5f);
            #pragma unroll
            for (int nt = 0; nt < 8; ++nt) v[nt] = (v[nt] - mu) * rs * lg[nt] + lb[nt];
        }
        if (m < M) {
            #pragma unroll
            for (int nt = 0; nt < 8; ++nt) {
                size_t o = (size_t)m * 128 + nt * 16 + cb;
                if (OF32) outf[o] = v[nt];
                if (OB16) outb[o] = f2b(v[nt]);
            }
        }
    }
}

// ---------------- fused GEMM chain: W from L2 (frag order), ONE barrier -----
// After the staging barrier, all LDS traffic (A-frags, epilogue rewrites) is
// band-local to the owning wave -> wave-lockstep makes it race-free.
__global__ __launch_bounds__(256)
void gc_chain(const unsigned short* __restrict__ hin, const unsigned short* __restrict__ aggb,
              unsigned short* __restrict__ hout,
              const unsigned short* __restrict__ Wl_f, const unsigned short* __restrict__ Wr_f,
              const unsigned short* __restrict__ W1_f, const unsigned short* __restrict__ W2_f,
              const float* __restrict__ bl,
              const float* __restrict__ g1, const float* __restrict__ b1,
              const float* __restrict__ bb1, const float* __restrict__ bb2,
              const float* __restrict__ g2, const float* __restrict__ b2, int M) {
    __shared__ short Hl[64 * 136];     // h tile -> y1 tile
    __shared__ short Gl[64 * 136];     // agg tile -> elu(t) tile

    const int t = threadIdx.x;
    const int lane = t & 63, wid = t >> 6;
    const int m0 = blockIdx.x * 64;
    const int cb = lane & 15, rq = lane >> 4;
    const int aoff_base = (wid * 16 + cb) * 136 + rq * 8;
    const int boff = lane * 8;

    for (int i = t; i < 1024; i += 256) {
        int row = i >> 4, seg = i & 15;
        int gr = m0 + row; if (gr >= M) gr = M - 1;
        *(uint4*)&Hl[row * 136 + seg * 8] = *(const uint4*)&hin[(size_t)gr * 128 + seg * 8];
        *(uint4*)&Gl[row * 136 + seg * 8] = *(const uint4*)&aggb[(size_t)gr * 128 + seg * 8];
    }
    __syncthreads();   // the only barrier

    f32x4 acc[8];
    #pragma unroll
    for (int nt = 0; nt < 8; ++nt) acc[nt] = (f32x4){0.f, 0.f, 0.f, 0.f};

    // ---- dual GEMM: acc = agg@Wl + h@Wr ----
    for (int kc = 0; kc < 4; ++kc) {
        short8 a0 = *(const short8*)&Gl[aoff_base + kc * 32];
        short8 a1 = *(const short8*)&Hl[aoff_base + kc * 32];
        #pragma unroll
        for (int nt = 0; nt < 8; ++nt) {
            const size_t wo = (size_t)(kc * 8 + nt) * 512 + boff;
            acc[nt] = __builtin_amdgcn_mfma_f32_16x16x32_bf16(a0, *(const short8*)&Wl_f[wo], acc[nt], 0, 0, 0);
            acc[nt] = __builtin_amdgcn_mfma_f32_16x16x32_bf16(a1, *(const short8*)&Wr_f[wo], acc[nt], 0, 0, 0);
        }
    }

    // ---- epilogue 1 (band-local): y1 = LN1(acc + bl + h) -> Hl + regs ----
    float y1r[4][8];
    {
        float bs[8], lg[8], lb[8];
        #pragma unroll
        for (int nt = 0; nt < 8; ++nt) {
            int col = nt * 16 + cb;
            bs[nt] = bl[col]; lg[nt] = g1[col]; lb[nt] = b1[col];
        }
        #pragma unroll
        for (int reg = 0; reg < 4; ++reg) {
            int r = wid * 16 + rq * 4 + reg;
            float v[8];
            float s1 = 0.f, s2 = 0.f;
            #pragma unroll
            for (int nt = 0; nt < 8; ++nt) {
                v[nt] = acc[nt][reg] + bs[nt] + us2f((unsigned short)Hl[r * 136 + nt * 16 + cb]);
                s1 += v[nt]; s2 += v[nt] * v[nt];
            }
            #pragma unroll
            for (int o = 8; o >= 1; o >>= 1) { s1 += __shfl_xor(s1, o); s2 += __shfl_xor(s2, o); }
            float mu = s1 * (1.f / 128.f);
            float rs = rsqrtf(s2 * (1.f / 128.f) - mu * mu + 1e-5f);
            #pragma unroll
            for (int nt = 0; nt < 8; ++nt) {
                float y = (v[nt] - mu) * rs * lg[nt] + lb[nt];
                y1r[reg][nt] = y;
                Hl[r * 136 + nt * 16 + cb] = (short)f2b(y);
            }
        }
    }

    // ---- FF1 (band-local): t = elu(y1@W1 + bb1) -> Gl ----
    #pragma unroll
    for (int nt = 0; nt < 8; ++nt) acc[nt] = (f32x4){0.f, 0.f, 0.f, 0.f};
    for (int kc = 0; kc < 4; ++kc) {
        short8 a0 = *(const short8*)&Hl[aoff_base + kc * 32];
        #pragma unroll
        for (int nt = 0; nt < 8; ++nt)
            acc[nt] = __builtin_amdgcn_mfma_f32_16x16x32_bf16(
                a0, *(const short8*)&W1_f[(size_t)(kc * 8 + nt) * 512 + boff], acc[nt], 0, 0, 0);
    }
    {
        float bs[8];
        #pragma unroll
        for (int nt = 0; nt < 8; ++nt) bs[nt] = bb1[nt * 16 + cb];
        #pragma unroll
        for (int reg = 0; reg < 4; ++reg) {
            int r = wid * 16 + rq * 4 + reg;
            #pragma unroll
            for (int nt = 0; nt < 8; ++nt) {
                float v = acc[nt][reg] + bs[nt];
                v = v > 0.f ? v : expm1f(v);
                Gl[r * 136 + nt * 16 + cb] = (short)f2b(v);
            }
        }
    }

    // ---- FF2 (band-local): h' = LN2(t@W2 + bb2 + y1) -> global ----
    #pragma unroll
    for (int nt = 0; nt < 8; ++nt) acc[nt] = (f32x4){0.f, 0.f, 0.f, 0.f};
    for (int kc = 0; kc < 4; ++kc) {
        short8 a0 = *(const short8*)&Gl[aoff_base + kc * 32];
        #pragma unroll
        for (int nt = 0; nt < 8; ++nt)
            acc[nt] = __builtin_amdgcn_mfma_f32_16x16x32_bf16(
                a0, *(const short8*)&W2_f[(size_t)(kc * 8 + nt) * 512 + boff], acc[nt], 0, 0, 0);
    }
    {
        float bs[8], lg[8], lb[8];
        #pragma unroll
        for (int nt = 0; nt < 8; ++nt) {
            int col = nt * 16 + cb;
            bs[nt] = bb2[col]; lg[nt] = g2[col]; lb[nt] = b2[col];
        }
        #pragma unroll
        for (int reg = 0; reg < 4; ++reg) {
            int r = wid * 16 + rq * 4 + reg;
            int m = m0 + r;
            float v[8];
            float s1 = 0.f, s2 = 0.f;
            #pragma unroll
            for (int nt = 0; nt < 8; ++nt) {
                v[nt] = acc[nt][reg] + bs[nt] + y1r[reg][nt];
                s1 += v[nt]; s2 += v[nt] * v[nt];
            }
            #pragma unroll
            for (int o = 8; o >= 1; o >>= 1) { s1 += __shfl_xor(s1, o); s2 += __shfl_xor(s2, o); }
            float mu = s1 * (1.f / 128.f);
            float rs = rsqrtf(s2 * (1.f / 128.f) - mu * mu + 1e-5f);
            if (m < M) {
                #pragma unroll
                for (int nt = 0; nt < 8; ++nt)
                    hout[(size_t)m * 128 + nt * 16 + cb] = f2b((v[nt] - mu) * rs * lg[nt] + lb[nt]);
            }
        }
    }
}

extern "C" void kernel_launch(void* const* d_in, const int* in_sizes, int n_in,
                              void* d_out, int out_size, void* d_ws, size_t ws_size,
                              hipStream_t stream) {
    const float* x      = (const float*)d_in[0];
    const float* w      = (const float*)d_in[1];
    const int*   ei     = (const int*)d_in[2];
    const int*   batch  = (const int*)d_in[3];
    const float* W_in   = (const float*)d_in[4];
    const float* b_in   = (const float*)d_in[5];
    const float* sage_Wl = (const float*)d_in[6];
    const float* sage_bl = (const float*)d_in[7];
    const float* sage_Wr = (const float*)d_in[8];
    const float* ln1_g  = (const float*)d_in[9];
    const float* ln1_b  = (const float*)d_in[10];
    const float* lin1_W = (const float*)d_in[11];
    const float* lin1_b = (const float*)d_in[12];
    const float* lin2_W = (const float*)d_in[13];
    const float* lin2_b = (const float*)d_in[14];
    const float* ln2_g  = (const float*)d_in[15];
    const float* ln2_b  = (const float*)d_in[16];
    const float* mdf_W  = (const float*)d_in[17];
    const float* mdf_b  = (const float*)d_in[18];
    const float* pln1_g = (const float*)d_in[19];
    const float* pln1_b = (const float*)d_in[20];
    const float* plin1_W = (const float*)d_in[21];
    const float* plin1_b = (const float*)d_in[22];
    const float* plin2_W = (const float*)d_in[23];
    const float* plin2_b = (const float*)d_in[24];
    const float* pln2_g = (const float*)d_in[25];
    const float* pln2_b = (const float*)d_in[26];
    float* out = (float*)d_out;

    const int* e_src = ei;
    const int* e_dst = ei + NE;

    // ---- workspace layout ----
    float* ws = (float*)d_ws;
    size_t off = 0;
    float* gm    = ws + off; off += (size_t)NG * FF;
    float* hh    = ws + off; off += (size_t)NG * FF;
    float* tt    = ws + off; off += (size_t)NG * FF;
    float* inv_deg = ws + off; off += NN;
    float* inv_cnt = ws + off; off += NG;
    unsigned short* us = (unsigned short*)(ws + off);
    size_t uoff = 0;
    unsigned short* hb0  = us + uoff; uoff += (size_t)NN * FF;
    unsigned short* hb1  = us + uoff; uoff += (size_t)NN * FF;
    unsigned short* aggb = us + uoff; uoff += (size_t)NN * FF;
    unsigned short* wt   = us + uoff; uoff += (size_t)16 * 16384;
    int* iw = (int*)(us + uoff);
    size_t ioff = 0;
    unsigned* pairs = (unsigned*)iw; ioff += (size_t)NBK * BCAP;
    int* ssrc    = iw + ioff; ioff += (size_t)NBK * BCAP;
    int* row_beg = iw + ioff; ioff += NN;
    int* row_end = iw + ioff; ioff += NN;
    int* g_off   = iw + ioff; ioff += NG + 1;
    int* bcur    = iw + ioff; ioff += NBK;

    // ---- weight prep (16 matrices -> frag-ordered bf16) ----
    WTab tab;
    tab.a[0] = W_in;
    for (int l = 0; l < 3; ++l) {
        tab.a[1 + l]  = sage_Wl + (size_t)l * 16384;
        tab.a[4 + l]  = sage_Wr + (size_t)l * 16384;
        tab.a[7 + l]  = lin1_W + (size_t)l * 16384;
        tab.a[10 + l] = lin2_W + (size_t)l * 16384;
    }
    tab.a[13] = mdf_W;      // first 128 rows only (Wa)
    tab.a[14] = plin1_W;
    tab.a[15] = plin2_W;
    prep_weights<<<16 * 64, 256, 0, stream>>>(tab, wt);
    const unsigned short* win_t = wt + 0 * 16384;
    const unsigned short* wa_t  = wt + 13 * 16384;
    const unsigned short* p1_t  = wt + 14 * 16384;
    const unsigned short* p2_t  = wt + 15 * 16384;

    // ---- build padded CSR (no histogram pass, no scan) ----
    init_bcur<<<1, 256, 0, stream>>>(bcur);
    graph_offsets<<<(NG + 256) / 256, 256, 0, stream>>>(batch, g_off, inv_cnt);
    radix_scatter<<<RB, 256, 0, stream>>>(e_src, e_dst, bcur, pairs, NE);
    bucket_build<<<NBK, 256, 0, stream>>>(pairs, bcur, row_beg, row_end, inv_deg, ssrc);

    const int GN = (NN + 63) / 64;     // 1563
    const int GB = NG / 64;            // 16

    // ---- input linear: hb0 = bf16(x @ W_in[0:128] + w * W_in[128] + b_in) ----
    gemm_mfma<false, true, 0, 0, false, false, true><<<GN, 256, 0, stream>>>(
        x, win_t, b_in, w, W_in + 128 * 128,
        nullptr, nullptr, nullptr, nullptr, hb0, NN);

    // ---- 3 GC blocks: gather (high-occupancy) + fused GEMM chain ----
    unsigned short* hcur = hb0;
    unsigned short* hnxt = hb1;
    for (int l = 0; l < 3; ++l) {
        sage_agg<<<NN / 4, 256, 0, stream>>>(hcur, row_beg, row_end, inv_deg, ssrc, aggb);
        gc_chain<<<GN, 256, 0, stream>>>(
            hcur, aggb, hnxt,
            wt + (size_t)(1 + l) * 16384, wt + (size_t)(4 + l) * 16384,
            wt + (size_t)(7 + l) * 16384, wt + (size_t)(10 + l) * 16384,
            sage_bl + (size_t)l * FF,
            ln1_g + (size_t)l * FF, ln1_b + (size_t)l * FF,
            lin1_b + (size_t)l * FF, lin2_b + (size_t)l * FF,
            ln2_g + (size_t)l * FF, ln2_b + (size_t)l * FF, NN);
        unsigned short* tmp = hcur; hcur = hnxt; hnxt = tmp;
    }

    // ---- head: pool(h2) == gm @ mdf_W[0:128] + mdf_b  (exact algebra) ----
    pool_mean_b<<<NG, 128, 0, stream>>>(hcur, g_off, inv_cnt, gm);
    gemm_mfma<false, false, 0, 0, true, true, false><<<GB, 256, 0, stream>>>(
        gm, wa_t, mdf_b, nullptr, nullptr,
        nullptr, pln1_g, pln1_b, hh, nullptr, NG);
    gemm_mfma<false, false, 0, 1, false, true, false><<<GB, 256, 0, stream>>>(
        hh, p1_t, plin1_b, nullptr, nullptr,
        nullptr, nullptr, nullptr, tt, nullptr, NG);
    gemm_mfma<false, false, 1, 0, true, true, false><<<GB, 256, 0, stream>>>(
        tt, p2_t, plin2_b, nullptr, nullptr,
        hh, pln2_g, pln2_b, out, nullptr, NG);
}

// Round 11
// 612.487 us; speedup vs baseline: 1.3793x; 1.0625x over previous
//
#include <hip/hip_runtime.h>
#include <math.h>

#define NN 100000
#define NE 1600000
#define NG 1024
#define FF 128
#define BSH 9
#define NBK ((NN + 511) >> BSH)   // 196 buckets of 512 nodes
#define RB 256                    // radix blocks
#define BCAP 16384                // fixed bucket capacity (mean 8192, sigma~90)

typedef __attribute__((ext_vector_type(8))) short short8;
typedef __attribute__((ext_vector_type(4))) float f32x4;
typedef __attribute__((ext_vector_type(2))) float f32x2;

__device__ __forceinline__ unsigned short f2b(float f) {
    union { float f; unsigned u; } v; v.f = f;
    unsigned r = (v.u + 0x7FFF + ((v.u >> 16) & 1)) >> 16;
    return (unsigned short)r;
}
__device__ __forceinline__ float us2f(unsigned short u) {
    union { unsigned u; float f; } v; v.u = ((unsigned)u) << 16; return v.f;
}
__device__ __forceinline__ float b2f_lo(unsigned u) {
    union { unsigned u; float f; } v; v.u = u << 16; return v.f;
}
__device__ __forceinline__ float b2f_hi(unsigned u) {
    union { unsigned u; float f; } v; v.u = u & 0xFFFF0000u; return v.f;
}
// decode 8 fp8 (uint2) -> accumulate into a[0..7]
__device__ __forceinline__ void acc8(float* a, uint2 u) {
    f32x2 p;
    p = __builtin_amdgcn_cvt_pk_f32_fp8(u.x, false); a[0] += p.x; a[1] += p.y;
    p = __builtin_amdgcn_cvt_pk_f32_fp8(u.x, true);  a[2] += p.x; a[3] += p.y;
    p = __builtin_amdgcn_cvt_pk_f32_fp8(u.y, false); a[4] += p.x; a[5] += p.y;
    p = __builtin_amdgcn_cvt_pk_f32_fp8(u.y, true);  a[6] += p.x; a[7] += p.y;
}
// pack 8 floats -> 8 fp8 (uint2), byte i = v[i]
__device__ __forceinline__ uint2 pk8(const float* v) {
    unsigned lo = 0, hi = 0;
    lo = (unsigned)__builtin_amdgcn_cvt_pk_fp8_f32(v[0], v[1], (int)lo, false);
    lo = (unsigned)__builtin_amdgcn_cvt_pk_fp8_f32(v[2], v[3], (int)lo, true);
    hi = (unsigned)__builtin_amdgcn_cvt_pk_fp8_f32(v[4], v[5], (int)hi, false);
    hi = (unsigned)__builtin_amdgcn_cvt_pk_fp8_f32(v[6], v[7], (int)hi, true);
    uint2 r; r.x = lo; r.y = hi; return r;
}

// ---------------- init bucket cursors to region bases -----------------------
__global__ void init_bcur(int* __restrict__ bcur) {
    int b = blockIdx.x * blockDim.x + threadIdx.x;
    if (b < NBK) bcur[b] = b * BCAP;
}

// ---------------- pass 1: scatter packed (src<<9|local) into padded buckets -
__global__ __launch_bounds__(256)
void radix_scatter(const int* __restrict__ src, const int* __restrict__ dst,
                   int* __restrict__ bcur, unsigned* __restrict__ pairs, int n) {
    __shared__ int base[NBK];
    __shared__ int cnt[NBK];
    for (int i = threadIdx.x; i < NBK; i += 256) cnt[i] = 0;
    __syncthreads();
    const int per = (n + RB - 1) / RB;
    const int beg = blockIdx.x * per;
    const int end = min(n, beg + per);
    for (int i = beg + threadIdx.x; i < end; i += 256)
        atomicAdd(&cnt[dst[i] >> BSH], 1);
    __syncthreads();
    for (int i = threadIdx.x; i < NBK; i += 256)
        base[i] = cnt[i] ? atomicAdd(&bcur[i], cnt[i]) : 0;
    __syncthreads();
    for (int i = beg + threadIdx.x; i < end; i += 256) {
        int d = dst[i];
        int p = atomicAdd(&base[d >> BSH], 1);
        pairs[p] = ((unsigned)src[i] << BSH) | (unsigned)(d & 511);
    }
}

// ---------------- pass 2: per-bucket hist+scan+scatter -> padded CSR --------
__global__ __launch_bounds__(256)
void bucket_build(const unsigned* __restrict__ pairs, const int* __restrict__ bcur,
                  int* __restrict__ row_beg, int* __restrict__ row_end,
                  float* __restrict__ inv_deg, int* __restrict__ ssrc) {
    __shared__ int cnt[512];
    __shared__ int curs[512];
    __shared__ int wsum[4];
    const int b = blockIdx.x;
    const int n0 = b << BSH;
    const int t = threadIdx.x;
    const int lane = t & 63, wid = t >> 6;

    for (int i = t; i < 512; i += 256) cnt[i] = 0;
    __syncthreads();
    const int beg = b * BCAP, end = bcur[b];
    for (int i = beg + t; i < end; i += 256)
        atomicAdd(&cnt[pairs[i] & 511], 1);
    __syncthreads();

    int c0 = cnt[2 * t], c1 = cnt[2 * t + 1];
    int v = c0 + c1;
    int x = v;
    #pragma unroll
    for (int o = 1; o < 64; o <<= 1) {
        int y = __shfl_up(x, o);
        if (lane >= o) x += y;
    }
    if (lane == 63) wsum[wid] = x;
    __syncthreads();
    if (t == 0) {
        int s = 0;
        #pragma unroll
        for (int w2 = 0; w2 < 4; ++w2) { int tv = wsum[w2]; wsum[w2] = s; s += tv; }
    }
    __syncthreads();
    int g0 = beg + wsum[wid] + x - v;
    int g1 = g0 + c0;
    curs[2 * t] = g0;
    curs[2 * t + 1] = g1;
    {
        int node = n0 + 2 * t;
        if (node < NN) {
            row_beg[node] = g0; row_end[node] = g1;
            inv_deg[node] = 1.0f / (float)(c0 > 1 ? c0 : 1);
        }
        node = n0 + 2 * t + 1;
        if (node < NN) {
            row_beg[node] = g1; row_end[node] = g1 + c1;
            inv_deg[node] = 1.0f / (float)(c1 > 1 ? c1 : 1);
        }
    }
    __syncthreads();
    for (int i = beg + t; i < end; i += 256) {
        unsigned pr = pairs[i];
        int p = atomicAdd(&curs[pr & 511], 1);
        ssrc[p] = (int)(pr >> BSH);
    }
}

// ---------------- graph offsets via binary search on sorted batch -----------
__global__ __launch_bounds__(256)
void graph_offsets(const int* __restrict__ batch, int* __restrict__ g_off,
                   float* __restrict__ inv_cnt) {
    int g = blockIdx.x * blockDim.x + threadIdx.x;
    if (g > NG) return;
    if (g == NG) { g_off[NG] = NN; return; }
    int lo = 0, hi = NN;
    while (lo < hi) { int mid = (lo + hi) >> 1; if (batch[mid] < g) lo = mid + 1; else hi = mid; }
    int lo2 = lo, hi2 = NN;
    while (lo2 < hi2) { int mid = (lo2 + hi2) >> 1; if (batch[mid] < g + 1) lo2 = mid + 1; else hi2 = mid; }
    g_off[g] = lo;
    int c = lo2 - lo;
    inv_cnt[g] = 1.0f / (float)(c > 1 ? c : 1);
}

// ---------------- weight prep: fp32 [k][n] -> bf16 MFMA-FRAGMENT order ------
struct WTab { const float* a[16]; };
__global__ __launch_bounds__(256)
void prep_weights(WTab tab, unsigned short* __restrict__ dst) {
    int w = blockIdx.x >> 6;
    int idx = ((blockIdx.x & 63) << 8) + threadIdx.x;
    int j = idx & 7, lane = (idx >> 3) & 63, nt = (idx >> 9) & 7, kc = idx >> 12;
    int cb = lane & 15, rq = lane >> 4;
    int k = kc * 32 + rq * 8 + j;
    int n = nt * 16 + cb;
    dst[(size_t)w * 16384 + idx] = f2b(tab.a[w][k * 128 + n]);
}

// ---------------- SAGE mean aggregation from fp8 shadow (permuted rows) -----
// h8 row layout: byte cb*8+nt holds col nt*16+cb. Lane j (=cb) reads uint2
// at j*8 -> cols {nt*16+j}. Gather traffic halved vs bf16.
__global__ __launch_bounds__(256)
void sage_agg(const unsigned char* __restrict__ h8, const int* __restrict__ row_beg,
              const int* __restrict__ row_end, const float* __restrict__ inv_deg,
              const int* __restrict__ ssrc, unsigned short* __restrict__ aggb) {
    const int wid = threadIdx.x >> 6;
    const int lane = threadIdx.x & 63;
    const int node = blockIdx.x * 4 + wid;
    const int eg = lane >> 4, j = lane & 15;
    const int beg = row_beg[node], end = row_end[node];
    float a[8] = {0.f, 0.f, 0.f, 0.f, 0.f, 0.f, 0.f, 0.f};
    int e = beg + eg;
    for (; e + 12 < end; e += 16) {
        int s0 = ssrc[e], s1 = ssrc[e + 4], s2 = ssrc[e + 8], s3 = ssrc[e + 12];
        uint2 u0 = *(const uint2*)&h8[(size_t)s0 * 128 + j * 8];
        uint2 u1 = *(const uint2*)&h8[(size_t)s1 * 128 + j * 8];
        uint2 u2 = *(const uint2*)&h8[(size_t)s2 * 128 + j * 8];
        uint2 u3 = *(const uint2*)&h8[(size_t)s3 * 128 + j * 8];
        acc8(a, u0); acc8(a, u1); acc8(a, u2); acc8(a, u3);
    }
    for (; e < end; e += 4) {
        uint2 u0 = *(const uint2*)&h8[(size_t)ssrc[e] * 128 + j * 8];
        acc8(a, u0);
    }
    #pragma unroll
    for (int k = 0; k < 8; ++k) {
        a[k] += __shfl_xor(a[k], 16);
        a[k] += __shfl_xor(a[k], 32);
    }
    if (eg == 0) {
        float id = inv_deg[node];
        #pragma unroll
        for (int nt = 0; nt < 8; ++nt)
            aggb[(size_t)node * 128 + nt * 16 + j] = f2b(a[nt] * id);
    }
}

// ---------------- mean pool per graph from bf16 ----------------
__global__ __launch_bounds__(128)
void pool_mean_b(const unsigned short* __restrict__ src, const int* __restrict__ g_off,
                 const float* __restrict__ inv_cnt, float* __restrict__ out) {
    const int g = blockIdx.x;
    const int j = threadIdx.x;
    const int beg = g_off[g], end = g_off[g + 1];
    float s = 0.f;
    for (int n = beg; n < end; ++n) s += us2f(src[(size_t)n * FF + j]);
    out[(size_t)g * FF + j] = s * inv_cnt[g];
}

// ---------------- MFMA bf16 GEMM, frag-ordered W from global ---------------
template<bool AB16, bool R1, int RESM, int ACT, bool LN, bool OF32, bool OB16, bool OB8>
__global__ __launch_bounds__(256)
void gemm_mfma(const void* __restrict__ A_,
               const unsigned short* __restrict__ Wf,
               const float* __restrict__ bias,
               const float* __restrict__ rvec, const float* __restrict__ rrow,
               const float* __restrict__ res,
               const float* __restrict__ lng, const float* __restrict__ lnb,
               float* __restrict__ outf, unsigned short* __restrict__ outb,
               unsigned char* __restrict__ outb8, int M) {
    __shared__ short Al[64 * 136];

    const int t = threadIdx.x;
    const int lane = t & 63, wid = t >> 6;
    const int m0 = blockIdx.x * 64;
    const int cb = lane & 15, rq = lane >> 4;

    if (AB16) {
        const unsigned short* Ab = (const unsigned short*)A_;
        for (int i = t; i < 1024; i += 256) {
            int row = i >> 4, seg = i & 15;
            int gr = m0 + row; if (gr >= M) gr = M - 1;
            *(uint4*)&Al[row * 136 + seg * 8] = *(const uint4*)&Ab[(size_t)gr * 128 + seg * 8];
        }
    } else {
        const float* Af = (const float*)A_;
        for (int i = t; i < 2048; i += 256) {
            int row = i >> 5, seg = i & 31;
            int gr = m0 + row; if (gr >= M) gr = M - 1;
            float4 v = *(const float4*)&Af[(size_t)gr * 128 + seg * 4];
            ushort4 o = {f2b(v.x), f2b(v.y), f2b(v.z), f2b(v.w)};
            *(ushort4*)&Al[row * 136 + seg * 4] = o;
        }
    }
    __syncthreads();

    f32x4 acc[8];
    #pragma unroll
    for (int nt = 0; nt < 8; ++nt) acc[nt] = (f32x4){0.f, 0.f, 0.f, 0.f};

    const int aoff_base = (wid * 16 + cb) * 136 + rq * 8;
    for (int kc = 0; kc < 4; ++kc) {
        short8 a0 = *(const short8*)&Al[aoff_base + kc * 32];
        #pragma unroll
        for (int nt = 0; nt < 8; ++nt) {
            short8 b0 = *(const short8*)&Wf[(size_t)(kc * 8 + nt) * 512 + lane * 8];
            acc[nt] = __builtin_amdgcn_mfma_f32_16x16x32_bf16(a0, b0, acc[nt], 0, 0, 0);
        }
    }

    float bs[8], rr[8], lg[8], lb[8];
    #pragma unroll
    for (int nt = 0; nt < 8; ++nt) {
        int col = nt * 16 + cb;
        bs[nt] = bias[col];
        if (R1) rr[nt] = rrow[col];
        if (LN) { lg[nt] = lng[col]; lb[nt] = lnb[col]; }
    }
    #pragma unroll
    for (int reg = 0; reg < 4; ++reg) {
        int m = m0 + wid * 16 + rq * 4 + reg;
        int mc = m < M ? m : M - 1;
        float v[8];
        #pragma unroll
        for (int nt = 0; nt < 8; ++nt) v[nt] = acc[nt][reg] + bs[nt];
        if (R1) {
            float rv = rvec[mc];
            #pragma unroll
            for (int nt = 0; nt < 8; ++nt) v[nt] += rv * rr[nt];
        }
        if (RESM == 1) {
            #pragma unroll
            for (int nt = 0; nt < 8; ++nt) v[nt] += res[(size_t)mc * 128 + nt * 16 + cb];
        }
        if (ACT == 1) {
            #pragma unroll
            for (int nt = 0; nt < 8; ++nt) v[nt] = v[nt] > 0.f ? v[nt] : expm1f(v[nt]);
        }
        if (LN) {
            float s1 = 0.f, s2 = 0.f;
            #pragma unroll
            for (int nt = 0; nt < 8; ++nt) { s1 += v[nt]; s2 += v[nt] * v[nt]; }
            #pragma unroll
            for (int o = 8; o >= 1; o >>= 1) { s1 += __shfl_xor(s1, o); s2 += __shfl_xor(s2, o); }
            float mu = s1 * (1.f / 128.f);
            float rs = rsqrtf(s2 * (1.f / 128.f) - mu * mu + 1e-5f);
            #pragma unroll
            for (int nt = 0; nt < 8; ++nt) v[nt] = (v[nt] - mu) * rs * lg[nt] + lb[nt];
        }
        if (m < M) {
            #pragma unroll
            for (int nt = 0; nt < 8; ++nt) {
                size_t o = (size_t)m * 128 + nt * 16 + cb;
                if (OF32) outf[o] = v[nt];
                if (OB16) outb[o] = f2b(v[nt]);
            }
            if (OB8) *(uint2*)&outb8[(size_t)m * 128 + cb * 8] = pk8(v);
        }
    }
}

// ---------------- fused GEMM chain: W from L2 (frag order), ONE barrier -----
__global__ __launch_bounds__(256)
void gc_chain(const unsigned short* __restrict__ hin, const unsigned short* __restrict__ aggb,
              unsigned short* __restrict__ hout, unsigned char* __restrict__ h8out,
              const unsigned short* __restrict__ Wl_f, const unsigned short* __restrict__ Wr_f,
              const unsigned short* __restrict__ W1_f, const unsigned short* __restrict__ W2_f,
              const float* __restrict__ bl,
              const float* __restrict__ g1, const float* __restrict__ b1,
              const float* __restrict__ bb1, const float* __restrict__ bb2,
              const float* __restrict__ g2, const float* __restrict__ b2, int M) {
    __shared__ short Hl[64 * 136];     // h tile -> y1 tile
    __shared__ short Gl[64 * 136];     // agg tile -> elu(t) tile

    const int t = threadIdx.x;
    const int lane = t & 63, wid = t >> 6;
    const int m0 = blockIdx.x * 64;
    const int cb = lane & 15, rq = lane >> 4;
    const int aoff_base = (wid * 16 + cb) * 136 + rq * 8;
    const int boff = lane * 8;

    for (int i = t; i < 1024; i += 256) {
        int row = i >> 4, seg = i & 15;
        int gr = m0 + row; if (gr >= M) gr = M - 1;
        *(uint4*)&Hl[row * 136 + seg * 8] = *(const uint4*)&hin[(size_t)gr * 128 + seg * 8];
        *(uint4*)&Gl[row * 136 + seg * 8] = *(const uint4*)&aggb[(size_t)gr * 128 + seg * 8];
    }
    __syncthreads();   // the only barrier

    f32x4 acc[8];
    #pragma unroll
    for (int nt = 0; nt < 8; ++nt) acc[nt] = (f32x4){0.f, 0.f, 0.f, 0.f};

    // ---- dual GEMM: acc = agg@Wl + h@Wr ----
    for (int kc = 0; kc < 4; ++kc) {
        short8 a0 = *(const short8*)&Gl[aoff_base + kc * 32];
        short8 a1 = *(const short8*)&Hl[aoff_base + kc * 32];
        #pragma unroll
        for (int nt = 0; nt < 8; ++nt) {
            const size_t wo = (size_t)(kc * 8 + nt) * 512 + boff;
            acc[nt] = __builtin_amdgcn_mfma_f32_16x16x32_bf16(a0, *(const short8*)&Wl_f[wo], acc[nt], 0, 0, 0);
            acc[nt] = __builtin_amdgcn_mfma_f32_16x16x32_bf16(a1, *(const short8*)&Wr_f[wo], acc[nt], 0, 0, 0);
        }
    }

    // ---- epilogue 1 (band-local): y1 = LN1(acc + bl + h) -> Hl + regs ----
    float y1r[4][8];
    {
        float bs[8], lg[8], lb[8];
        #pragma unroll
        for (int nt = 0; nt < 8; ++nt) {
            int col = nt * 16 + cb;
            bs[nt] = bl[col]; lg[nt] = g1[col]; lb[nt] = b1[col];
        }
        #pragma unroll
        for (int reg = 0; reg < 4; ++reg) {
            int r = wid * 16 + rq * 4 + reg;
            float v[8];
            float s1 = 0.f, s2 = 0.f;
            #pragma unroll
            for (int nt = 0; nt < 8; ++nt) {
                v[nt] = acc[nt][reg] + bs[nt] + us2f((unsigned short)Hl[r * 136 + nt * 16 + cb]);
                s1 += v[nt]; s2 += v[nt] * v[nt];
            }
            #pragma unroll
            for (int o = 8; o >= 1; o >>= 1) { s1 += __shfl_xor(s1, o); s2 += __shfl_xor(s2, o); }
            float mu = s1 * (1.f / 128.f);
            float rs = rsqrtf(s2 * (1.f / 128.f) - mu * mu + 1e-5f);
            #pragma unroll
            for (int nt = 0; nt < 8; ++nt) {
                float y = (v[nt] - mu) * rs * lg[nt] + lb[nt];
                y1r[reg][nt] = y;
                Hl[r * 136 + nt * 16 + cb] = (short)f2b(y);
            }
        }
    }

    // ---- FF1 (band-local): t = elu(y1@W1 + bb1) -> Gl ----
    #pragma unroll
    for (int nt = 0; nt < 8; ++nt) acc[nt] = (f32x4){0.f, 0.f, 0.f, 0.f};
    for (int kc = 0; kc < 4; ++kc) {
        short8 a0 = *(const short8*)&Hl[aoff_base + kc * 32];
        #pragma unroll
        for (int nt = 0; nt < 8; ++nt)
            acc[nt] = __builtin_amdgcn_mfma_f32_16x16x32_bf16(
                a0, *(const short8*)&W1_f[(size_t)(kc * 8 + nt) * 512 + boff], acc[nt], 0, 0, 0);
    }
    {
        float bs[8];
        #pragma unroll
        for (int nt = 0; nt < 8; ++nt) bs[nt] = bb1[nt * 16 + cb];
        #pragma unroll
        for (int reg = 0; reg < 4; ++reg) {
            int r = wid * 16 + rq * 4 + reg;
            #pragma unroll
            for (int nt = 0; nt < 8; ++nt) {
                float v = acc[nt][reg] + bs[nt];
                v = v > 0.f ? v : expm1f(v);
                Gl[r * 136 + nt * 16 + cb] = (short)f2b(v);
            }
        }
    }

    // ---- FF2 (band-local): h' = LN2(t@W2 + bb2 + y1) -> global bf16 + fp8 --
    #pragma unroll
    for (int nt = 0; nt < 8; ++nt) acc[nt] = (f32x4){0.f, 0.f, 0.f, 0.f};
    for (int kc = 0; kc < 4; ++kc) {
        short8 a0 = *(const short8*)&Gl[aoff_base + kc * 32];
        #pragma unroll
        for (int nt = 0; nt < 8; ++nt)
            acc[nt] = __builtin_amdgcn_mfma_f32_16x16x32_bf16(
                a0, *(const short8*)&W2_f[(size_t)(kc * 8 + nt) * 512 + boff], acc[nt], 0, 0, 0);
    }
    {
        float bs[8], lg[8], lb[8];
        #pragma unroll
        for (int nt = 0; nt < 8; ++nt) {
            int col = nt * 16 + cb;
            bs[nt] = bb2[col]; lg[nt] = g2[col]; lb[nt] = b2[col];
        }
        #pragma unroll
        for (int reg = 0; reg < 4; ++reg) {
            int r = wid * 16 + rq * 4 + reg;
            int m = m0 + r;
            float v[8];
            float s1 = 0.f, s2 = 0.f;
            #pragma unroll
            for (int nt = 0; nt < 8; ++nt) {
                v[nt] = acc[nt][reg] + bs[nt] + y1r[reg][nt];
                s1 += v[nt]; s2 += v[nt] * v[nt];
            }
            #pragma unroll
            for (int o = 8; o >= 1; o >>= 1) { s1 += __shfl_xor(s1, o); s2 += __shfl_xor(s2, o); }
            float mu = s1 * (1.f / 128.f);
            float rs = rsqrtf(s2 * (1.f / 128.f) - mu * mu + 1e-5f);
            if (m < M) {
                float fv[8];
                #pragma unroll
                for (int nt = 0; nt < 8; ++nt) {
                    fv[nt] = (v[nt] - mu) * rs * lg[nt] + lb[nt];
                    hout[(size_t)m * 128 + nt * 16 + cb] = f2b(fv[nt]);
                }
                *(uint2*)&h8out[(size_t)m * 128 + cb * 8] = pk8(fv);
            }
        }
    }
}

extern "C" void kernel_launch(void* const* d_in, const int* in_sizes, int n_in,
                              void* d_out, int out_size, void* d_ws, size_t ws_size,
                              hipStream_t stream) {
    const float* x      = (const float*)d_in[0];
    const float* w      = (const float*)d_in[1];
    const int*   ei     = (const int*)d_in[2];
    const int*   batch  = (const int*)d_in[3];
    const float* W_in   = (const float*)d_in[4];
    const float* b_in   = (const float*)d_in[5];
    const float* sage_Wl = (const float*)d_in[6];
    const float* sage_bl = (const float*)d_in[7];
    const float* sage_Wr = (const float*)d_in[8];
    const float* ln1_g  = (const float*)d_in[9];
    const float* ln1_b  = (const float*)d_in[10];
    const float* lin1_W = (const float*)d_in[11];
    const float* lin1_b = (const float*)d_in[12];
    const float* lin2_W = (const float*)d_in[13];
    const float* lin2_b = (const float*)d_in[14];
    const float* ln2_g  = (const float*)d_in[15];
    const float* ln2_b  = (const float*)d_in[16];
    const float* mdf_W  = (const float*)d_in[17];
    const float* mdf_b  = (const float*)d_in[18];
    const float* pln1_g = (const float*)d_in[19];
    const float* pln1_b = (const float*)d_in[20];
    const float* plin1_W = (const float*)d_in[21];
    const float* plin1_b = (const float*)d_in[22];
    const float* plin2_W = (const float*)d_in[23];
    const float* plin2_b = (const float*)d_in[24];
    const float* pln2_g = (const float*)d_in[25];
    const float* pln2_b = (const float*)d_in[26];
    float* out = (float*)d_out;

    const int* e_src = ei;
    const int* e_dst = ei + NE;

    // ---- workspace layout ----
    float* ws = (float*)d_ws;
    size_t off = 0;
    float* gm    = ws + off; off += (size_t)NG * FF;
    float* hh    = ws + off; off += (size_t)NG * FF;
    float* tt    = ws + off; off += (size_t)NG * FF;
    float* inv_deg = ws + off; off += NN;
    float* inv_cnt = ws + off; off += NG;
    unsigned short* us = (unsigned short*)(ws + off);
    size_t uoff = 0;
    unsigned short* hb0  = us + uoff; uoff += (size_t)NN * FF;
    unsigned short* hb1  = us + uoff; uoff += (size_t)NN * FF;
    unsigned short* aggb = us + uoff; uoff += (size_t)NN * FF;
    unsigned short* wt   = us + uoff; uoff += (size_t)16 * 16384;
    int* iw = (int*)(us + uoff);
    size_t ioff = 0;
    unsigned* pairs = (unsigned*)iw; ioff += (size_t)NBK * BCAP;
    int* ssrc    = iw + ioff; ioff += (size_t)NBK * BCAP;
    int* row_beg = iw + ioff; ioff += NN;
    int* row_end = iw + ioff; ioff += NN;
    int* g_off   = iw + ioff; ioff += NG + 1;
    int* bcur    = iw + ioff; ioff += NBK;
    // h8 (12.8 MB) aliases pairs (12.85 MB): pairs is dead after bucket_build,
    // h8 is first written by the input GEMM which runs after.
    unsigned char* h8 = (unsigned char*)pairs;

    // ---- weight prep (16 matrices -> frag-ordered bf16) ----
    WTab tab;
    tab.a[0] = W_in;
    for (int l = 0; l < 3; ++l) {
        tab.a[1 + l]  = sage_Wl + (size_t)l * 16384;
        tab.a[4 + l]  = sage_Wr + (size_t)l * 16384;
        tab.a[7 + l]  = lin1_W + (size_t)l * 16384;
        tab.a[10 + l] = lin2_W + (size_t)l * 16384;
    }
    tab.a[13] = mdf_W;      // first 128 rows only (Wa)
    tab.a[14] = plin1_W;
    tab.a[15] = plin2_W;
    prep_weights<<<16 * 64, 256, 0, stream>>>(tab, wt);
    const unsigned short* win_t = wt + 0 * 16384;
    const unsigned short* wa_t  = wt + 13 * 16384;
    const unsigned short* p1_t  = wt + 14 * 16384;
    const unsigned short* p2_t  = wt + 15 * 16384;

    // ---- build padded CSR (no histogram pass, no scan) ----
    init_bcur<<<1, 256, 0, stream>>>(bcur);
    graph_offsets<<<(NG + 256) / 256, 256, 0, stream>>>(batch, g_off, inv_cnt);
    radix_scatter<<<RB, 256, 0, stream>>>(e_src, e_dst, bcur, pairs, NE);
    bucket_build<<<NBK, 256, 0, stream>>>(pairs, bcur, row_beg, row_end, inv_deg, ssrc);

    const int GN = (NN + 63) / 64;     // 1563
    const int GB = NG / 64;            // 16

    // ---- input linear: hb0 (bf16) + h8 (fp8, permuted) ----
    gemm_mfma<false, true, 0, 0, false, false, true, true><<<GN, 256, 0, stream>>>(
        x, win_t, b_in, w, W_in + 128 * 128,
        nullptr, nullptr, nullptr, nullptr, hb0, h8, NN);

    // ---- 3 GC blocks: fp8 gather + fused GEMM chain ----
    unsigned short* hcur = hb0;
    unsigned short* hnxt = hb1;
    for (int l = 0; l < 3; ++l) {
        sage_agg<<<NN / 4, 256, 0, stream>>>(h8, row_beg, row_end, inv_deg, ssrc, aggb);
        gc_chain<<<GN, 256, 0, stream>>>(
            hcur, aggb, hnxt, h8,
            wt + (size_t)(1 + l) * 16384, wt + (size_t)(4 + l) * 16384,
            wt + (size_t)(7 + l) * 16384, wt + (size_t)(10 + l) * 16384,
            sage_bl + (size_t)l * FF,
            ln1_g + (size_t)l * FF, ln1_b + (size_t)l * FF,
            lin1_b + (size_t)l * FF, lin2_b + (size_t)l * FF,
            ln2_g + (size_t)l * FF, ln2_b + (size_t)l * FF, NN);
        unsigned short* tmp = hcur; hcur = hnxt; hnxt = tmp;
    }

    // ---- head: pool(h2) == gm @ mdf_W[0:128] + mdf_b  (exact algebra) ----
    pool_mean_b<<<NG, 128, 0, stream>>>(hcur, g_off, inv_cnt, gm);
    gemm_mfma<false, false, 0, 0, true, true, false, false><<<GB, 256, 0, stream>>>(
        gm, wa_t, mdf_b, nullptr, nullptr,
        nullptr, pln1_g, pln1_b, hh, nullptr, nullptr, NG);
    gemm_mfma<false, false, 0, 1, false, true, false, false><<<GB, 256, 0, stream>>>(
        hh, p1_t, plin1_b, nullptr, nullptr,
        nullptr, nullptr, nullptr, tt, nullptr, nullptr, NG);
    gemm_mfma<false, false, 1, 0, true, true, false, false><<<GB, 256, 0, stream>>>(
        tt, p2_t, plin2_b, nullptr, nullptr,
        hh, pln2_g, pln2_b, out, nullptr, nullptr, NG);
}